// Round 5
// baseline (460.388 us; speedup 1.0000x reference)
//
#include <hip/hip_runtime.h>
#include <hip/hip_bf16.h>
#include <math.h>

typedef __hip_bfloat16 bf16;
typedef __bf16 bf16x4 __attribute__((ext_vector_type(4)));
typedef __bf16 bf16x8 __attribute__((ext_vector_type(8)));
typedef float f32x4 __attribute__((ext_vector_type(4)));
typedef float f32x16 __attribute__((ext_vector_type(16)));
typedef unsigned short us4 __attribute__((ext_vector_type(4)));

#define LOG2E 1.44269504088896340736f

#if defined(__has_builtin)
#if __has_builtin(__builtin_amdgcn_exp2f)
#define EXP2(x) __builtin_amdgcn_exp2f(x)
#else
#define EXP2(x) exp2f(x)
#endif
#else
#define EXP2(x) exp2f(x)
#endif

__device__ inline __bf16 f2b(float f) {
  __hip_bfloat16 h = __float2bfloat16(f);
  return *reinterpret_cast<__bf16*>(&h);
}
__device__ inline unsigned short b2u(float f) {  // RNE (cold paths)
  __hip_bfloat16 h = __float2bfloat16(f);
  return *reinterpret_cast<unsigned short*>(&h);
}
__device__ inline unsigned short b2u_fast(float f) {  // round-half-up (hot loop)
  union { float f; unsigned u; } v;
  v.f = f;
  return (unsigned short)((v.u + 0x8000u) >> 16);
}
// 16B logical LDS read as two 8B reads (2-way-bank-friendly padded strides)
__device__ inline bf16x8 ld16(const bf16* p) {
  bf16x4 lo = *(const bf16x4*)p;
  bf16x4 hi = *(const bf16x4*)(p + 4);
  return __builtin_shufflevector(lo, hi, 0, 1, 2, 3, 4, 5, 6, 7);
}
__device__ inline void st16(bf16* p, uint4 v) {
  *(uint2*)p = make_uint2(v.x, v.y);
  *(uint2*)(p + 4) = make_uint2(v.z, v.w);
}
__device__ inline us4 shfl32_us4(us4 v) {
  uint2 u = *(uint2*)&v;
  u.x = __shfl_xor(u.x, 32);
  u.y = __shfl_xor(u.y, 32);
  return *(us4*)&u;
}
__device__ inline bf16x8 mk8(us4 lo, us4 hi) {
  bf16x4 l = *(bf16x4*)&lo;
  bf16x4 h = *(bf16x4*)&hi;
  return __builtin_shufflevector(l, h, 0, 1, 2, 3, 4, 5, 6, 7);
}

// ---------------- prep: weight transpose+cast (z<3) + T5 bias LUT (z==3) ----------------
__global__ void prep_k(const float* __restrict__ Wq, const float* __restrict__ Wkv,
                       const float* __restrict__ Wo, const float* __restrict__ rel_bias,
                       bf16* __restrict__ WqT, bf16* __restrict__ WkvT,
                       bf16* __restrict__ WoT, float* __restrict__ lut) {
  __shared__ float tile[32][33];
  int z = blockIdx.z;
  int tx = threadIdx.x, ty = threadIdx.y;
  if (z == 3) {  // T5 bias LUT (f64 bucketing = np ref), pre-scaled by log2e
    if (blockIdx.y != 0 || blockIdx.x >= 16) return;
    int r = blockIdx.x * 256 + ty * 32 + tx;
    int rel = r - 2048;
    int bkt = rel > 0 ? 16 : 0;
    int ar = rel < 0 ? -rel : rel;
    int idx;
    if (ar < 8) {
      idx = bkt + ar;
    } else {
      double t = log((double)ar / 8.0) / log(16.0) * 8.0;
      int lg = 8 + (int)t;
      if (lg > 15) lg = 15;
      idx = bkt + lg;
    }
    for (int h = 0; h < 16; ++h)
      lut[h * 4096 + r] = rel_bias[idx * 16 + h] * LOG2E;
    return;
  }
  const float* in = z == 0 ? Wq : (z == 1 ? Wkv : Wo);
  bf16* out = z == 0 ? WqT : (z == 1 ? WkvT : WoT);
  int cols = z == 1 ? 2048 : 1024;
  int c0 = blockIdx.x * 32;
  if (c0 >= cols) return;
  int r0 = blockIdx.y * 32;
  for (int i = ty; i < 32; i += 8)
    tile[i][tx] = in[(size_t)(r0 + i) * cols + c0 + tx];
  __syncthreads();
  for (int i = ty; i < 32; i += 8)
    out[(size_t)(c0 + i) * 1024 + r0 + tx] = __float2bfloat16(tile[tx][i]);
}

// ---------------- fused Q+KV projection GEMM ----------------
// grid (32, 24): y<8 -> Q (x log2e) -> Qb[b,h,s,d]; y>=8: gn<1024 -> Kb[b,h,k,d],
// gn>=1024 -> Vt[b,h,d,k]. Q/K use swapped-operand MFMA (D^T) for packed epilogue.
// A read directly from f32 inputs, cast during staging (no separate cast pass).
// LDS tiles padded to stride 36 bf16 (72B): bank = (18*row + 4*cg) mod 32 ->
// max 2-way aliasing (free) for BOTH st16 writes and ld16 frag reads. (The old
// unpadded stride-32 layout was an 8-way conflict on every LDS op: 3.1M
// SQ_LDS_BANK_CONFLICT measured.) Both A and B reg-staged with one-step
// prefetch: loads for k+1 issue right after the staging barrier (T14).
#define PS 36
__global__ __launch_bounds__(256, 3) void gemm_qkv_k(const float* __restrict__ hf,
                                                     const float* __restrict__ kvf,
                                                     const bf16* __restrict__ WqT,
                                                     const bf16* __restrict__ WkvT,
                                                     bf16* __restrict__ Qb,
                                                     bf16* __restrict__ Kb,
                                                     bf16* __restrict__ Vt) {
  __shared__ __align__(16) bf16 As[128 * PS];
  __shared__ __align__(16) bf16 Bs[128 * PS];
  const int tid = threadIdx.x;
  const int lane = tid & 63;
  const int w = tid >> 6;
  const int wm = (w >> 1) * 64;
  const int wn = (w & 1) * 64;
  const int l15 = lane & 15;
  const int quad = lane >> 4;
  const int srow = lane >> 2;
  const int skg = lane & 3;

  const bool isQ = blockIdx.y < 8;
  const float* A = isQ ? hf : kvf;
  const bf16* Bt = isQ ? WqT : WkvT;
  const int n0 = (isQ ? blockIdx.y : blockIdx.y - 8) * 128;
  const int m0 = blockIdx.x * 128;
  const bool isV = (!isQ) && (n0 >= 1024);

  f32x4 acc[4][4];
#pragma unroll
  for (int i = 0; i < 4; ++i)
#pragma unroll
    for (int j = 0; j < 4; ++j) acc[i][j] = (f32x4){0.f, 0.f, 0.f, 0.f};

  float4 pa[2][2];
  uint4 pb[2];
  auto LOAD = [&](int k0) {
#pragma unroll
    for (int rep = 0; rep < 2; ++rep) {
      int seg = w * 2 + rep;
      const float* src = A + (size_t)(m0 + seg * 16 + srow) * 1024 + k0 + skg * 8;
      pa[rep][0] = *(const float4*)src;
      pa[rep][1] = *(const float4*)(src + 4);
      pb[rep] = *(const uint4*)(Bt + (size_t)(n0 + seg * 16 + srow) * 1024 + k0 + skg * 8);
    }
  };
  LOAD(0);

  for (int k0 = 0; k0 < 1024; k0 += 32) {
    __syncthreads();  // prev frag reads done
#pragma unroll
    for (int rep = 0; rep < 2; ++rep) {
      int seg = w * 2 + rep;
      bf16x8 v;
      v[0] = f2b(pa[rep][0].x); v[1] = f2b(pa[rep][0].y);
      v[2] = f2b(pa[rep][0].z); v[3] = f2b(pa[rep][0].w);
      v[4] = f2b(pa[rep][1].x); v[5] = f2b(pa[rep][1].y);
      v[6] = f2b(pa[rep][1].z); v[7] = f2b(pa[rep][1].w);
      st16(As + (seg * 16 + srow) * PS + skg * 8, *(uint4*)&v);
      st16(Bs + (seg * 16 + srow) * PS + skg * 8, pb[rep]);
    }
    __syncthreads();
    if (k0 + 32 < 1024) LOAD(k0 + 32);  // prefetch; hides under MFMAs
    bf16x8 af[4], bfr[4];
#pragma unroll
    for (int i = 0; i < 4; ++i)
      af[i] = ld16(As + (wm + i * 16 + l15) * PS + quad * 8);
#pragma unroll
    for (int j = 0; j < 4; ++j)
      bfr[j] = ld16(Bs + (wn + j * 16 + l15) * PS + quad * 8);
    if (isV) {  // normal: lane regs vary gm (=k of V) for packed V^T store
#pragma unroll
      for (int i = 0; i < 4; ++i)
#pragma unroll
        for (int j = 0; j < 4; ++j)
          acc[i][j] = __builtin_amdgcn_mfma_f32_16x16x32_bf16(af[i], bfr[j], acc[i][j], 0, 0, 0);
    } else {  // swapped: D^T, lane regs vary gn (=d) for packed Q/K store
#pragma unroll
      for (int i = 0; i < 4; ++i)
#pragma unroll
        for (int j = 0; j < 4; ++j)
          acc[i][j] = __builtin_amdgcn_mfma_f32_16x16x32_bf16(bfr[j], af[i], acc[i][j], 0, 0, 0);
    }
  }

  if (isV) {  // V -> [b,h,d,k], 4 consecutive k per 8B store
#pragma unroll
    for (int i = 0; i < 4; ++i) {
      int gmb = m0 + wm + i * 16 + quad * 4;
      int b = gmb >> 11, kp = gmb & 2047;
#pragma unroll
      for (int j = 0; j < 4; ++j) {
        int gn = n0 + wn + j * 16 + l15;
        int h = (gn >> 6) & 15, d = gn & 63;
        us4 pk;
#pragma unroll
        for (int r = 0; r < 4; ++r) pk[r] = b2u(acc[i][j][r]);
        *(us4*)(Vt + ((((size_t)b * 16 + h) * 64 + d) << 11) + kp) = pk;
      }
    }
    return;
  }
  // Q/K swapped epilogue: gm = ..+l15 (s), gn = ..+quad*4+r (d packed)
  const float scale = isQ ? LOG2E : 1.0f;
  bf16* dst = isQ ? Qb : Kb;
#pragma unroll
  for (int i = 0; i < 4; ++i) {
    int gm = m0 + wm + i * 16 + l15;
    int b = gm >> 11, s = gm & 2047;
#pragma unroll
    for (int j = 0; j < 4; ++j) {
      int gn = n0 + wn + j * 16 + quad * 4;
      int h = (gn >> 6) & 15, d0 = gn & 63;
      us4 pk;
#pragma unroll
      for (int r = 0; r < 4; ++r) pk[r] = b2u(acc[i][j][r] * scale);
      *(us4*)(dst + ((((size_t)b * 16 + h) * 2048 + s) << 6) + d0) = pk;
    }
  }
}

// ---------------- O projection: out[4096][1024] = Ob * WoT^T, 128x64 tiles ----------------
// Same padded-LDS + reg-staged prefetch treatment; swapped-operand MFMA -> float4 stores
__global__ __launch_bounds__(256, 3) void gemm_o_k(const bf16* __restrict__ A,
                                                   const bf16* __restrict__ Bt,
                                                   float* __restrict__ C0) {
  __shared__ __align__(16) bf16 As[128 * PS];
  __shared__ __align__(16) bf16 Bs[64 * PS];
  const int tid = threadIdx.x;
  const int lane = tid & 63;
  const int w = tid >> 6;
  const int wm = w * 32;
  const int m0 = blockIdx.x * 128;
  const int n0 = blockIdx.y * 64;
  const int l15 = lane & 15;
  const int quad = lane >> 4;
  const int srow = lane >> 2;
  const int skg = lane & 3;

  f32x4 acc[2][4];
#pragma unroll
  for (int i = 0; i < 2; ++i)
#pragma unroll
    for (int j = 0; j < 4; ++j) acc[i][j] = (f32x4){0.f, 0.f, 0.f, 0.f};

  uint4 pa[2], pbo;
  auto LOAD = [&](int k0) {
#pragma unroll
    for (int rep = 0; rep < 2; ++rep) {
      int seg = w * 2 + rep;
      pa[rep] = *(const uint4*)(A + (size_t)(m0 + seg * 16 + srow) * 1024 + k0 + skg * 8);
    }
    pbo = *(const uint4*)(Bt + (size_t)(n0 + w * 16 + srow) * 1024 + k0 + skg * 8);
  };
  LOAD(0);

  for (int k0 = 0; k0 < 1024; k0 += 32) {
    __syncthreads();
#pragma unroll
    for (int rep = 0; rep < 2; ++rep) {
      int seg = w * 2 + rep;
      st16(As + (seg * 16 + srow) * PS + skg * 8, pa[rep]);
    }
    st16(Bs + (w * 16 + srow) * PS + skg * 8, pbo);
    __syncthreads();
    if (k0 + 32 < 1024) LOAD(k0 + 32);
    bf16x8 af[2], bfr[4];
#pragma unroll
    for (int i = 0; i < 2; ++i)
      af[i] = ld16(As + (wm + i * 16 + l15) * PS + quad * 8);
#pragma unroll
    for (int j = 0; j < 4; ++j)
      bfr[j] = ld16(Bs + (j * 16 + l15) * PS + quad * 8);
#pragma unroll
    for (int i = 0; i < 2; ++i)
#pragma unroll
      for (int j = 0; j < 4; ++j)
        acc[i][j] = __builtin_amdgcn_mfma_f32_16x16x32_bf16(bfr[j], af[i], acc[i][j], 0, 0, 0);
  }
#pragma unroll
  for (int i = 0; i < 2; ++i) {
    int gm = m0 + wm + i * 16 + l15;
#pragma unroll
    for (int j = 0; j < 4; ++j) {
      int gn = n0 + j * 16 + quad * 4;
      *(f32x4*)(C0 + (size_t)gm * 1024 + gn) = acc[i][j];
    }
  }
}

// ---------------- fused attention, transposed-S, streamed softmax, NO max tracking ----------------
// 8 waves / 512 threads: waves 0-3 (kg=0) process even 128-k tiles, waves 4-7
// (kg=1) odd tiles, each group with private Ks/Vs LDS buffer. Wave wq owns
// q-strip [qb+wq*32,+32); lane owns one q (col=lane&31).
// Softmax uses FIXED m=0 (scores bounded ~|25| by construction; exact softmax
// for any consistent m). End: group 1 dumps (l,O) to LDS; group 0 merges.
// LDS: lbias[2176]f32 | Ks[2][128*STK] | Vs[2][64*SVK] = 78336 B (2 blocks/CU).
#define STK 68
#define SVK 136
#define KS_OFF 8704
#define VS_OFF 43520
__global__ __launch_bounds__(512, 4) void attn_k(const bf16* __restrict__ Qb,
                                                 const bf16* __restrict__ Kb,
                                                 const bf16* __restrict__ Vt,
                                                 const float* __restrict__ lut,
                                                 bf16* __restrict__ Ob) {
  __shared__ __align__(16) char smem[78336];
  float* lbias = (float*)smem;
  bf16* Ksb = (bf16*)(smem + KS_OFF);  // [2][128*STK]
  bf16* Vsb = (bf16*)(smem + VS_OFF);  // [2][64*SVK]

  const int tid = threadIdx.x;
  const int lane = tid & 63;
  const int w = tid >> 6;    // 0..7
  const int wq = w & 3;      // q-strip within block
  const int kg = w >> 2;     // k-group: 0 = even tiles, 1 = odd tiles
  const int t256 = tid & 255;
  const int q31 = lane & 31;
  const int half = lane >> 5;

  bf16* Ks = Ksb + kg * (128 * STK);
  bf16* Vs = Vsb + kg * (64 * SVK);

  const int qt = blockIdx.x;  // 0..15
  const int bh = blockIdx.y;  // 0..31
  const int h = bh & 15, b = bh >> 4;
  const int qb = qt * 128;

  const int gbase = h * 4096 + 1921 - qb;
  for (int t = tid; t < 2175; t += 512) lbias[t] = lut[gbase + t];

  const size_t base = (size_t)bh * 2048 * 64;   // Qb/Kb rows
  const size_t vbase = (size_t)bh * 64 * 2048;  // Vt rows
  const int qg = qb + wq * 32 + q31;

  // Q B-frags (pre-scaled by log2e in projection)
  bf16x8 qf[4];
#pragma unroll
  for (int c = 0; c < 4; ++c)
    qf[c] = *(const bf16x8*)(Qb + base + (size_t)qg * 64 + c * 16 + half * 8);

  f32x16 oacc[2];
#pragma unroll
  for (int dj = 0; dj < 2; ++dj)
#pragma unroll
    for (int r = 0; r < 16; ++r) oacc[dj][r] = 0.f;
  float l_run = 0.f;

  const int kt0 = kg * 128;  // group's first tile

  for (int it = 0; it < 8; ++it) {
    const int kt = it * 256 + kt0;  // this group's k-tile base
    __syncthreads();  // all waves done reading their Ks/Vs
    {  // stage: issue both K and V loads, one wait, write LDS (no cross-tile regs)
      uint4 kr[4], vr[4];
#pragma unroll
      for (int rep = 0; rep < 4; ++rep) {
        int slot = t256 + rep * 256;
        kr[rep] = *(const uint4*)(Kb + base + (size_t)(kt + (slot >> 3)) * 64 + (slot & 7) * 8);
        vr[rep] = *(const uint4*)(Vt + vbase + (size_t)(slot >> 4) * 2048 + kt + (slot & 15) * 8);
      }
#pragma unroll
      for (int rep = 0; rep < 4; ++rep) {
        int slot = t256 + rep * 256;
        st16(Ks + (slot >> 3) * STK + (slot & 7) * 8, kr[rep]);
        st16(Vs + (slot >> 4) * SVK + (slot & 15) * 8, vr[rep]);
      }
    }
    __syncthreads();

    const int xbase = kt + 127 + 4 * half - wq * 32 - q31;
#pragma unroll
    for (int mt = 0; mt < 4; ++mt) {
      // S^T = K·Q^T for this 32-k mt-tile; bias pre-loaded in the accumulator
      f32x16 sacc;
#pragma unroll
      for (int a2 = 0; a2 < 4; ++a2)
#pragma unroll
        for (int rr = 0; rr < 4; ++rr)
          sacc[4 * a2 + rr] = lbias[xbase + mt * 32 + 8 * a2 + rr];
#pragma unroll
      for (int c = 0; c < 4; ++c) {
        bf16x8 kf = ld16(Ks + (mt * 32 + q31) * STK + c * 16 + half * 8);
        sacc = __builtin_amdgcn_mfma_f32_32x32x16_bf16(kf, qf[c], sacc, 0, 0, 0);
      }

      // exp (m=0, no subtract) + sum (4 parallel accumulators) + pack quads
      us4 ownq[4];
      f32x4 sv = (f32x4){0.f, 0.f, 0.f, 0.f};
#pragma unroll
      for (int a = 0; a < 4; ++a) {
        us4 pk;
#pragma unroll
        for (int rr = 0; rr < 4; ++rr) {
          float p = EXP2(sacc[4 * a + rr]);
          sv[rr] += p;
          pk[rr] = b2u_fast(p);
        }
        ownq[a] = pk;
      }
      l_run += (sv[0] + sv[1]) + (sv[2] + sv[3]);

      // exchange complementary k-quads across the half boundary (no LDS)
      us4 rcv0 = shfl32_us4(half ? ownq[0] : ownq[1]);
      us4 rcv1 = shfl32_us4(half ? ownq[2] : ownq[3]);

      // O^T += V^T·P^T for this mt's two 16-k chunks
#pragma unroll
      for (int p = 0; p < 2; ++p) {
        us4 rc = p ? rcv1 : rcv0;
        bf16x8 pfc = half ? mk8(rc, ownq[2 * p + 1]) : mk8(ownq[2 * p], rc);
#pragma unroll
        for (int dj = 0; dj < 2; ++dj) {
          bf16x8 vf = ld16(Vs + (dj * 32 + q31) * SVK + (mt * 2 + p) * 16 + half * 8);
          oacc[dj] = __builtin_amdgcn_mfma_f32_32x32x16_bf16(vf, pfc, oacc[dj], 0, 0, 0);
        }
      }
    }
  }

  // pair-sum of l (one shfl at the end)
  l_run += __shfl_xor(l_run, 32);

  // ---- merge the two k-groups (group 1 -> LDS -> group 0 combines) ----
  __syncthreads();  // everyone done with Ks/Vs/lbias
  float* mbuf = (float*)smem;  // 4 waves * 64 lanes * 35 f32 = 35840 B (< 78336)
  if (kg) {
    float* p = mbuf + ((size_t)(wq * 64 + lane)) * 35;  // stride 35: 2-way banks, free
    p[0] = l_run;
#pragma unroll
    for (int dj = 0; dj < 2; ++dj)
#pragma unroll
      for (int r = 0; r < 16; ++r) p[1 + dj * 16 + r] = oacc[dj][r];
  }
  __syncthreads();
  if (kg) return;

  const float* p = mbuf + ((size_t)(wq * 64 + lane)) * 35;
  float inv = 1.0f / (l_run + p[0]);

  // epilogue: O[qg][d] = (O0+O1)/(l0+l1), 8B packed stores
#pragma unroll
  for (int dj = 0; dj < 2; ++dj)
#pragma unroll
    for (int g = 0; g < 4; ++g) {
      us4 pk;
#pragma unroll
      for (int rr = 0; rr < 4; ++rr)
        pk[rr] = b2u((oacc[dj][4 * g + rr] + p[1 + dj * 16 + 4 * g + rr]) * inv);
      int d0 = dj * 32 + 8 * g + 4 * half;
      *(us4*)(Ob + ((size_t)(b * 2048 + qg)) * 1024 + h * 64 + d0) = pk;
    }
}

// ---------------- launch ----------------
extern "C" void kernel_launch(void* const* d_in, const int* in_sizes, int n_in,
                              void* d_out, int out_size, void* d_ws, size_t ws_size,
                              hipStream_t stream) {
  const float* hidden = (const float*)d_in[0];
  const float* kvs    = (const float*)d_in[1];
  const float* Wq     = (const float*)d_in[2];
  const float* Wkv    = (const float*)d_in[3];
  const float* Wo     = (const float*)d_in[4];
  const float* relb   = (const float*)d_in[5];
  float* out = (float*)d_out;

  char* ws = (char*)d_ws;
  bf16* WqT  = (bf16*)(ws + (size_t)0);           // 2 MB
  bf16* WkvT = (bf16*)(ws + ((size_t)2 << 20));   // 4 MB
  bf16* WoT  = (bf16*)(ws + ((size_t)6 << 20));   // 2 MB
  bf16* Ob   = (bf16*)(ws + ((size_t)8 << 20));   // 8 MB [B,S,E]
  bf16* Qb   = (bf16*)(ws + ((size_t)16 << 20));  // 8 MB [B,H,S,D]
  bf16* Kb   = (bf16*)(ws + ((size_t)24 << 20));  // 8 MB [B,H,K,D]
  bf16* Vt   = (bf16*)(ws + ((size_t)32 << 20));  // 8 MB [B,H,D,K]
  float* LUT = (float*)(ws + ((size_t)40 << 20)); // 256 KB

  // weights transpose+cast + bias LUT, one launch
  prep_k<<<dim3(64, 32, 4), dim3(32, 8), 0, stream>>>(Wq, Wkv, Wo, relb, WqT, WkvT, WoT, LUT);
  // Q (x log2e), K, V projections — reads f32 inputs directly (cast fused)
  gemm_qkv_k<<<dim3(32, 24), 256, 0, stream>>>(hidden, kvs, WqT, WkvT, Qb, Kb, Vt);
  // attention -> Ob
  attn_k<<<dim3(16, 32), 512, 0, stream>>>(Qb, Kb, Vt, LUT, Ob);
  // out = Ob @ Wo
  gemm_o_k<<<dim3(32, 16), 256, 0, stream>>>(Ob, WoT, out);
}

// Round 6
// 427.913 us; speedup vs baseline: 1.0759x; 1.0759x over previous
//
#include <hip/hip_runtime.h>
#include <hip/hip_bf16.h>
#include <math.h>

typedef __hip_bfloat16 bf16;
typedef __bf16 bf16x4 __attribute__((ext_vector_type(4)));
typedef __bf16 bf16x8 __attribute__((ext_vector_type(8)));
typedef float f32x4 __attribute__((ext_vector_type(4)));
typedef float f32x16 __attribute__((ext_vector_type(16)));
typedef unsigned short us4 __attribute__((ext_vector_type(4)));

#define LOG2E 1.44269504088896340736f

#if defined(__has_builtin)
#if __has_builtin(__builtin_amdgcn_exp2f)
#define EXP2(x) __builtin_amdgcn_exp2f(x)
#else
#define EXP2(x) exp2f(x)
#endif
#else
#define EXP2(x) exp2f(x)
#endif

__device__ inline __bf16 f2b(float f) {
  __hip_bfloat16 h = __float2bfloat16(f);
  return *reinterpret_cast<__bf16*>(&h);
}
__device__ inline unsigned short b2u(float f) {  // RNE (cold paths)
  __hip_bfloat16 h = __float2bfloat16(f);
  return *reinterpret_cast<unsigned short*>(&h);
}
__device__ inline unsigned short b2u_fast(float f) {  // round-half-up (hot loop)
  union { float f; unsigned u; } v;
  v.f = f;
  return (unsigned short)((v.u + 0x8000u) >> 16);
}
// 16B logical LDS read as two 8B reads (2-way-bank-friendly padded strides)
__device__ inline bf16x8 ld16(const bf16* p) {
  bf16x4 lo = *(const bf16x4*)p;
  bf16x4 hi = *(const bf16x4*)(p + 4);
  return __builtin_shufflevector(lo, hi, 0, 1, 2, 3, 4, 5, 6, 7);
}
__device__ inline void st16(bf16* p, uint4 v) {
  *(uint2*)p = make_uint2(v.x, v.y);
  *(uint2*)(p + 4) = make_uint2(v.z, v.w);
}
__device__ inline us4 shfl32_us4(us4 v) {
  uint2 u = *(uint2*)&v;
  u.x = __shfl_xor(u.x, 32);
  u.y = __shfl_xor(u.y, 32);
  return *(us4*)&u;
}
__device__ inline bf16x8 mk8(us4 lo, us4 hi) {
  bf16x4 l = *(bf16x4*)&lo;
  bf16x4 h = *(bf16x4*)&hi;
  return __builtin_shufflevector(l, h, 0, 1, 2, 3, 4, 5, 6, 7);
}
__device__ inline uint4 cvt8(float4 a0, float4 a1) {
  bf16x8 v;
  v[0] = f2b(a0.x); v[1] = f2b(a0.y); v[2] = f2b(a0.z); v[3] = f2b(a0.w);
  v[4] = f2b(a1.x); v[5] = f2b(a1.y); v[6] = f2b(a1.z); v[7] = f2b(a1.w);
  return *(uint4*)&v;
}

// ---------------- prep: weight transpose+cast (z<3) + T5 bias LUT (z==3) ----------------
__global__ void prep_k(const float* __restrict__ Wq, const float* __restrict__ Wkv,
                       const float* __restrict__ Wo, const float* __restrict__ rel_bias,
                       bf16* __restrict__ WqT, bf16* __restrict__ WkvT,
                       bf16* __restrict__ WoT, float* __restrict__ lut) {
  __shared__ float tile[32][33];
  int z = blockIdx.z;
  int tx = threadIdx.x, ty = threadIdx.y;
  if (z == 3) {  // T5 bias LUT (f64 bucketing = np ref), pre-scaled by log2e
    if (blockIdx.y != 0 || blockIdx.x >= 16) return;
    int r = blockIdx.x * 256 + ty * 32 + tx;
    int rel = r - 2048;
    int bkt = rel > 0 ? 16 : 0;
    int ar = rel < 0 ? -rel : rel;
    int idx;
    if (ar < 8) {
      idx = bkt + ar;
    } else {
      double t = log((double)ar / 8.0) / log(16.0) * 8.0;
      int lg = 8 + (int)t;
      if (lg > 15) lg = 15;
      idx = bkt + lg;
    }
    for (int h = 0; h < 16; ++h)
      lut[h * 4096 + r] = rel_bias[idx * 16 + h] * LOG2E;
    return;
  }
  const float* in = z == 0 ? Wq : (z == 1 ? Wkv : Wo);
  bf16* out = z == 0 ? WqT : (z == 1 ? WkvT : WoT);
  int cols = z == 1 ? 2048 : 1024;
  int c0 = blockIdx.x * 32;
  if (c0 >= cols) return;
  int r0 = blockIdx.y * 32;
  for (int i = ty; i < 32; i += 8)
    tile[i][tx] = in[(size_t)(r0 + i) * cols + c0 + tx];
  __syncthreads();
  for (int i = ty; i < 32; i += 8)
    out[(size_t)(c0 + i) * 1024 + r0 + tx] = __float2bfloat16(tile[tx][i]);
}

// ---------------- fused Q+KV projection GEMM ----------------
// grid (32, 24): y<8 -> Q (x log2e) -> Qb[b,h,s,d]; y>=8: gn<1024 -> Kb[b,h,k,d],
// gn>=1024 -> Vt[b,h,d,k]. Q/K use swapped-operand MFMA (D^T) for packed epilogue.
// A read directly from f32 inputs, cast during staging (no separate cast pass).
// LDS tiles padded to stride 36 bf16 (72B): minimal bank aliasing for both
// st16 writes and ld16 frag reads. One-step register prefetch held in NAMED
// SCALARS (pa0..pb1) -- NOT arrays/lambda-captures, which round-5 proved go
// to scratch (867 MB spill traffic, 3.6x slowdown).
#define PS 36
__global__ __launch_bounds__(256, 3) void gemm_qkv_k(const float* __restrict__ hf,
                                                     const float* __restrict__ kvf,
                                                     const bf16* __restrict__ WqT,
                                                     const bf16* __restrict__ WkvT,
                                                     bf16* __restrict__ Qb,
                                                     bf16* __restrict__ Kb,
                                                     bf16* __restrict__ Vt) {
  __shared__ __align__(16) bf16 As[128 * PS];
  __shared__ __align__(16) bf16 Bs[128 * PS];
  const int tid = threadIdx.x;
  const int lane = tid & 63;
  const int w = tid >> 6;
  const int wm = (w >> 1) * 64;
  const int wn = (w & 1) * 64;
  const int l15 = lane & 15;
  const int quad = lane >> 4;
  const int srow = lane >> 2;
  const int skg = lane & 3;

  const bool isQ = blockIdx.y < 8;
  const float* A = isQ ? hf : kvf;
  const bf16* Bt = isQ ? WqT : WkvT;
  const int n0 = (isQ ? blockIdx.y : blockIdx.y - 8) * 128;
  const int m0 = blockIdx.x * 128;
  const bool isV = (!isQ) && (n0 >= 1024);

  f32x4 acc[4][4];
#pragma unroll
  for (int i = 0; i < 4; ++i)
#pragma unroll
    for (int j = 0; j < 4; ++j) acc[i][j] = (f32x4){0.f, 0.f, 0.f, 0.f};

  // per-thread source pointers (seg0 = w*2, seg1 = w*2+1)
  const float* aptr0 = A + (size_t)(m0 + (w * 2) * 16 + srow) * 1024 + skg * 8;
  const float* aptr1 = aptr0 + 16 * 1024;
  const bf16* bptr0 = Bt + (size_t)(n0 + (w * 2) * 16 + srow) * 1024 + skg * 8;
  const bf16* bptr1 = bptr0 + 16 * 1024;
  bf16* awr0 = As + ((w * 2) * 16 + srow) * PS + skg * 8;
  bf16* awr1 = As + ((w * 2 + 1) * 16 + srow) * PS + skg * 8;
  bf16* bwr0 = Bs + ((w * 2) * 16 + srow) * PS + skg * 8;
  bf16* bwr1 = Bs + ((w * 2 + 1) * 16 + srow) * PS + skg * 8;

  // prologue prefetch (named scalars: stays in VGPRs)
  float4 pa0 = *(const float4*)(aptr0);
  float4 pa1 = *(const float4*)(aptr0 + 4);
  float4 pa2 = *(const float4*)(aptr1);
  float4 pa3 = *(const float4*)(aptr1 + 4);
  uint4 pb0 = *(const uint4*)(bptr0);
  uint4 pb1 = *(const uint4*)(bptr1);

  for (int k0 = 0; k0 < 1024; k0 += 32) {
    __syncthreads();  // prev frag reads done
    st16(awr0, cvt8(pa0, pa1));
    st16(awr1, cvt8(pa2, pa3));
    st16(bwr0, pb0);
    st16(bwr1, pb1);
    __syncthreads();
    if (k0 + 32 < 1024) {  // prefetch next step; hides under MFMAs
      int kn = k0 + 32;
      pa0 = *(const float4*)(aptr0 + kn);
      pa1 = *(const float4*)(aptr0 + kn + 4);
      pa2 = *(const float4*)(aptr1 + kn);
      pa3 = *(const float4*)(aptr1 + kn + 4);
      pb0 = *(const uint4*)(bptr0 + kn);
      pb1 = *(const uint4*)(bptr1 + kn);
    }
    bf16x8 af[4], bfr[4];
#pragma unroll
    for (int i = 0; i < 4; ++i)
      af[i] = ld16(As + (wm + i * 16 + l15) * PS + quad * 8);
#pragma unroll
    for (int j = 0; j < 4; ++j)
      bfr[j] = ld16(Bs + (wn + j * 16 + l15) * PS + quad * 8);
    if (isV) {  // normal: lane regs vary gm (=k of V) for packed V^T store
#pragma unroll
      for (int i = 0; i < 4; ++i)
#pragma unroll
        for (int j = 0; j < 4; ++j)
          acc[i][j] = __builtin_amdgcn_mfma_f32_16x16x32_bf16(af[i], bfr[j], acc[i][j], 0, 0, 0);
    } else {  // swapped: D^T, lane regs vary gn (=d) for packed Q/K store
#pragma unroll
      for (int i = 0; i < 4; ++i)
#pragma unroll
        for (int j = 0; j < 4; ++j)
          acc[i][j] = __builtin_amdgcn_mfma_f32_16x16x32_bf16(bfr[j], af[i], acc[i][j], 0, 0, 0);
    }
  }

  if (isV) {  // V -> [b,h,d,k], 4 consecutive k per 8B store
#pragma unroll
    for (int i = 0; i < 4; ++i) {
      int gmb = m0 + wm + i * 16 + quad * 4;
      int b = gmb >> 11, kp = gmb & 2047;
#pragma unroll
      for (int j = 0; j < 4; ++j) {
        int gn = n0 + wn + j * 16 + l15;
        int h = (gn >> 6) & 15, d = gn & 63;
        us4 pk;
#pragma unroll
        for (int r = 0; r < 4; ++r) pk[r] = b2u(acc[i][j][r]);
        *(us4*)(Vt + ((((size_t)b * 16 + h) * 64 + d) << 11) + kp) = pk;
      }
    }
    return;
  }
  // Q/K swapped epilogue: gm = ..+l15 (s), gn = ..+quad*4+r (d packed)
  const float scale = isQ ? LOG2E : 1.0f;
  bf16* dst = isQ ? Qb : Kb;
#pragma unroll
  for (int i = 0; i < 4; ++i) {
    int gm = m0 + wm + i * 16 + l15;
    int b = gm >> 11, s = gm & 2047;
#pragma unroll
    for (int j = 0; j < 4; ++j) {
      int gn = n0 + wn + j * 16 + quad * 4;
      int h = (gn >> 6) & 15, d0 = gn & 63;
      us4 pk;
#pragma unroll
      for (int r = 0; r < 4; ++r) pk[r] = b2u(acc[i][j][r] * scale);
      *(us4*)(dst + ((((size_t)b * 16 + h) * 2048 + s) << 6) + d0) = pk;
    }
  }
}

// ---------------- O projection: out[4096][1024] = Ob * WoT^T, 128x64 tiles ----------------
// Same padded-LDS + named-scalar prefetch; swapped-operand MFMA -> float4 stores
__global__ __launch_bounds__(256, 3) void gemm_o_k(const bf16* __restrict__ A,
                                                   const bf16* __restrict__ Bt,
                                                   float* __restrict__ C0) {
  __shared__ __align__(16) bf16 As[128 * PS];
  __shared__ __align__(16) bf16 Bs[64 * PS];
  const int tid = threadIdx.x;
  const int lane = tid & 63;
  const int w = tid >> 6;
  const int wm = w * 32;
  const int m0 = blockIdx.x * 128;
  const int n0 = blockIdx.y * 64;
  const int l15 = lane & 15;
  const int quad = lane >> 4;
  const int srow = lane >> 2;
  const int skg = lane & 3;

  f32x4 acc[2][4];
#pragma unroll
  for (int i = 0; i < 2; ++i)
#pragma unroll
    for (int j = 0; j < 4; ++j) acc[i][j] = (f32x4){0.f, 0.f, 0.f, 0.f};

  const bf16* aptr0 = A + (size_t)(m0 + (w * 2) * 16 + srow) * 1024 + skg * 8;
  const bf16* aptr1 = aptr0 + 16 * 1024;
  const bf16* bptr = Bt + (size_t)(n0 + w * 16 + srow) * 1024 + skg * 8;
  bf16* awr0 = As + ((w * 2) * 16 + srow) * PS + skg * 8;
  bf16* awr1 = As + ((w * 2 + 1) * 16 + srow) * PS + skg * 8;
  bf16* bwr = Bs + (w * 16 + srow) * PS + skg * 8;

  uint4 po0 = *(const uint4*)(aptr0);
  uint4 po1 = *(const uint4*)(aptr1);
  uint4 pbo = *(const uint4*)(bptr);

  for (int k0 = 0; k0 < 1024; k0 += 32) {
    __syncthreads();
    st16(awr0, po0);
    st16(awr1, po1);
    st16(bwr, pbo);
    __syncthreads();
    if (k0 + 32 < 1024) {
      int kn = k0 + 32;
      po0 = *(const uint4*)(aptr0 + kn);
      po1 = *(const uint4*)(aptr1 + kn);
      pbo = *(const uint4*)(bptr + kn);
    }
    bf16x8 af[2], bfr[4];
#pragma unroll
    for (int i = 0; i < 2; ++i)
      af[i] = ld16(As + (wm + i * 16 + l15) * PS + quad * 8);
#pragma unroll
    for (int j = 0; j < 4; ++j)
      bfr[j] = ld16(Bs + (j * 16 + l15) * PS + quad * 8);
#pragma unroll
    for (int i = 0; i < 2; ++i)
#pragma unroll
      for (int j = 0; j < 4; ++j)
        acc[i][j] = __builtin_amdgcn_mfma_f32_16x16x32_bf16(bfr[j], af[i], acc[i][j], 0, 0, 0);
  }
#pragma unroll
  for (int i = 0; i < 2; ++i) {
    int gm = m0 + wm + i * 16 + l15;
#pragma unroll
    for (int j = 0; j < 4; ++j) {
      int gn = n0 + j * 16 + quad * 4;
      *(f32x4*)(C0 + (size_t)gm * 1024 + gn) = acc[i][j];
    }
  }
}

// ---------------- fused attention, transposed-S, streamed softmax, NO max tracking ----------------
// 8 waves / 512 threads: waves 0-3 (kg=0) process even 128-k tiles, waves 4-7
// (kg=1) odd tiles, each group with private Ks/Vs LDS buffer. Wave wq owns
// q-strip [qb+wq*32,+32); lane owns one q (col=lane&31).
// Softmax uses FIXED m=0 (scores bounded ~|25| by construction; exact softmax
// for any consistent m). End: group 1 dumps (l,O) to LDS; group 0 merges.
// LDS: lbias[2176]f32 | Ks[2][128*STK] | Vs[2][64*SVK] = 78336 B (2 blocks/CU).
#define STK 68
#define SVK 136
#define KS_OFF 8704
#define VS_OFF 43520
__global__ __launch_bounds__(512, 4) void attn_k(const bf16* __restrict__ Qb,
                                                 const bf16* __restrict__ Kb,
                                                 const bf16* __restrict__ Vt,
                                                 const float* __restrict__ lut,
                                                 bf16* __restrict__ Ob) {
  __shared__ __align__(16) char smem[78336];
  float* lbias = (float*)smem;
  bf16* Ksb = (bf16*)(smem + KS_OFF);  // [2][128*STK]
  bf16* Vsb = (bf16*)(smem + VS_OFF);  // [2][64*SVK]

  const int tid = threadIdx.x;
  const int lane = tid & 63;
  const int w = tid >> 6;    // 0..7
  const int wq = w & 3;      // q-strip within block
  const int kg = w >> 2;     // k-group: 0 = even tiles, 1 = odd tiles
  const int t256 = tid & 255;
  const int q31 = lane & 31;
  const int half = lane >> 5;

  bf16* Ks = Ksb + kg * (128 * STK);
  bf16* Vs = Vsb + kg * (64 * SVK);

  const int qt = blockIdx.x;  // 0..15
  const int bh = blockIdx.y;  // 0..31
  const int h = bh & 15, b = bh >> 4;
  const int qb = qt * 128;

  const int gbase = h * 4096 + 1921 - qb;
  for (int t = tid; t < 2175; t += 512) lbias[t] = lut[gbase + t];

  const size_t base = (size_t)bh * 2048 * 64;   // Qb/Kb rows
  const size_t vbase = (size_t)bh * 64 * 2048;  // Vt rows
  const int qg = qb + wq * 32 + q31;

  // Q B-frags (pre-scaled by log2e in projection)
  bf16x8 qf[4];
#pragma unroll
  for (int c = 0; c < 4; ++c)
    qf[c] = *(const bf16x8*)(Qb + base + (size_t)qg * 64 + c * 16 + half * 8);

  f32x16 oacc[2];
#pragma unroll
  for (int dj = 0; dj < 2; ++dj)
#pragma unroll
    for (int r = 0; r < 16; ++r) oacc[dj][r] = 0.f;
  float l_run = 0.f;

  const int kt0 = kg * 128;  // group's first tile

  for (int it = 0; it < 8; ++it) {
    const int kt = it * 256 + kt0;  // this group's k-tile base
    __syncthreads();  // all waves done reading their Ks/Vs
    {  // stage: issue both K and V loads, one wait, write LDS (no cross-tile regs)
      uint4 kr[4], vr[4];
#pragma unroll
      for (int rep = 0; rep < 4; ++rep) {
        int slot = t256 + rep * 256;
        kr[rep] = *(const uint4*)(Kb + base + (size_t)(kt + (slot >> 3)) * 64 + (slot & 7) * 8);
        vr[rep] = *(const uint4*)(Vt + vbase + (size_t)(slot >> 4) * 2048 + kt + (slot & 15) * 8);
      }
#pragma unroll
      for (int rep = 0; rep < 4; ++rep) {
        int slot = t256 + rep * 256;
        st16(Ks + (slot >> 3) * STK + (slot & 7) * 8, kr[rep]);
        st16(Vs + (slot >> 4) * SVK + (slot & 15) * 8, vr[rep]);
      }
    }
    __syncthreads();

    const int xbase = kt + 127 + 4 * half - wq * 32 - q31;
#pragma unroll
    for (int mt = 0; mt < 4; ++mt) {
      // S^T = K·Q^T for this 32-k mt-tile; bias pre-loaded in the accumulator
      f32x16 sacc;
#pragma unroll
      for (int a2 = 0; a2 < 4; ++a2)
#pragma unroll
        for (int rr = 0; rr < 4; ++rr)
          sacc[4 * a2 + rr] = lbias[xbase + mt * 32 + 8 * a2 + rr];
#pragma unroll
      for (int c = 0; c < 4; ++c) {
        bf16x8 kf = ld16(Ks + (mt * 32 + q31) * STK + c * 16 + half * 8);
        sacc = __builtin_amdgcn_mfma_f32_32x32x16_bf16(kf, qf[c], sacc, 0, 0, 0);
      }

      // exp (m=0, no subtract) + sum (4 parallel accumulators) + pack quads
      us4 ownq[4];
      f32x4 sv = (f32x4){0.f, 0.f, 0.f, 0.f};
#pragma unroll
      for (int a = 0; a < 4; ++a) {
        us4 pk;
#pragma unroll
        for (int rr = 0; rr < 4; ++rr) {
          float p = EXP2(sacc[4 * a + rr]);
          sv[rr] += p;
          pk[rr] = b2u_fast(p);
        }
        ownq[a] = pk;
      }
      l_run += (sv[0] + sv[1]) + (sv[2] + sv[3]);

      // exchange complementary k-quads across the half boundary (no LDS)
      us4 rcv0 = shfl32_us4(half ? ownq[0] : ownq[1]);
      us4 rcv1 = shfl32_us4(half ? ownq[2] : ownq[3]);

      // O^T += V^T·P^T for this mt's two 16-k chunks
#pragma unroll
      for (int p = 0; p < 2; ++p) {
        us4 rc = p ? rcv1 : rcv0;
        bf16x8 pfc = half ? mk8(rc, ownq[2 * p + 1]) : mk8(ownq[2 * p], rc);
#pragma unroll
        for (int dj = 0; dj < 2; ++dj) {
          bf16x8 vf = ld16(Vs + (dj * 32 + q31) * SVK + (mt * 2 + p) * 16 + half * 8);
          oacc[dj] = __builtin_amdgcn_mfma_f32_32x32x16_bf16(vf, pfc, oacc[dj], 0, 0, 0);
        }
      }
    }
  }

  // pair-sum of l (one shfl at the end)
  l_run += __shfl_xor(l_run, 32);

  // ---- merge the two k-groups (group 1 -> LDS -> group 0 combines) ----
  __syncthreads();  // everyone done with Ks/Vs/lbias
  float* mbuf = (float*)smem;  // 4 waves * 64 lanes * 35 f32 = 35840 B (< 78336)
  if (kg) {
    float* p = mbuf + ((size_t)(wq * 64 + lane)) * 35;  // stride 35: 2-way banks, free
    p[0] = l_run;
#pragma unroll
    for (int dj = 0; dj < 2; ++dj)
#pragma unroll
      for (int r = 0; r < 16; ++r) p[1 + dj * 16 + r] = oacc[dj][r];
  }
  __syncthreads();
  if (kg) return;

  const float* p = mbuf + ((size_t)(wq * 64 + lane)) * 35;
  float inv = 1.0f / (l_run + p[0]);

  // epilogue: O[qg][d] = (O0+O1)/(l0+l1), 8B packed stores
#pragma unroll
  for (int dj = 0; dj < 2; ++dj)
#pragma unroll
    for (int g = 0; g < 4; ++g) {
      us4 pk;
#pragma unroll
      for (int rr = 0; rr < 4; ++rr)
        pk[rr] = b2u((oacc[dj][4 * g + rr] + p[1 + dj * 16 + 4 * g + rr]) * inv);
      int d0 = dj * 32 + 8 * g + 4 * half;
      *(us4*)(Ob + ((size_t)(b * 2048 + qg)) * 1024 + h * 64 + d0) = pk;
    }
}

// ---------------- launch ----------------
extern "C" void kernel_launch(void* const* d_in, const int* in_sizes, int n_in,
                              void* d_out, int out_size, void* d_ws, size_t ws_size,
                              hipStream_t stream) {
  const float* hidden = (const float*)d_in[0];
  const float* kvs    = (const float*)d_in[1];
  const float* Wq     = (const float*)d_in[2];
  const float* Wkv    = (const float*)d_in[3];
  const float* Wo     = (const float*)d_in[4];
  const float* relb   = (const float*)d_in[5];
  float* out = (float*)d_out;

  char* ws = (char*)d_ws;
  bf16* WqT  = (bf16*)(ws + (size_t)0);           // 2 MB
  bf16* WkvT = (bf16*)(ws + ((size_t)2 << 20));   // 4 MB
  bf16* WoT  = (bf16*)(ws + ((size_t)6 << 20));   // 2 MB
  bf16* Ob   = (bf16*)(ws + ((size_t)8 << 20));   // 8 MB [B,S,E]
  bf16* Qb   = (bf16*)(ws + ((size_t)16 << 20));  // 8 MB [B,H,S,D]
  bf16* Kb   = (bf16*)(ws + ((size_t)24 << 20));  // 8 MB [B,H,K,D]
  bf16* Vt   = (bf16*)(ws + ((size_t)32 << 20));  // 8 MB [B,H,D,K]
  float* LUT = (float*)(ws + ((size_t)40 << 20)); // 256 KB

  // weights transpose+cast + bias LUT, one launch
  prep_k<<<dim3(64, 32, 4), dim3(32, 8), 0, stream>>>(Wq, Wkv, Wo, relb, WqT, WkvT, WoT, LUT);
  // Q (x log2e), K, V projections — reads f32 inputs directly (cast fused)
  gemm_qkv_k<<<dim3(32, 24), 256, 0, stream>>>(hidden, kvs, WqT, WkvT, Qb, Kb, Vt);
  // attention -> Ob
  attn_k<<<dim3(16, 32), 512, 0, stream>>>(Qb, Kb, Vt, LUT, Ob);
  // out = Ob @ Wo
  gemm_o_k<<<dim3(32, 16), 256, 0, stream>>>(Ob, WoT, out);
}

// Round 7
// 223.301 us; speedup vs baseline: 2.0617x; 1.9163x over previous
//
#include <hip/hip_runtime.h>
#include <hip/hip_bf16.h>
#include <math.h>

typedef __hip_bfloat16 bf16;
typedef __bf16 bf16x4 __attribute__((ext_vector_type(4)));
typedef __bf16 bf16x8 __attribute__((ext_vector_type(8)));
typedef float f32x4 __attribute__((ext_vector_type(4)));
typedef float f32x16 __attribute__((ext_vector_type(16)));
typedef unsigned short us4 __attribute__((ext_vector_type(4)));

#define LOG2E 1.44269504088896340736f

#if defined(__has_builtin)
#if __has_builtin(__builtin_amdgcn_exp2f)
#define EXP2(x) __builtin_amdgcn_exp2f(x)
#else
#define EXP2(x) exp2f(x)
#endif
#else
#define EXP2(x) exp2f(x)
#endif

// NOTE on __launch_bounds__ (measured on this toolchain, rounds 2/4/5/6):
// the 2nd arg caps VGPRs at ~256/arg2 (arg2=4 -> 64 regs, arg2=3 -> 84),
// NOT the 512-unified/waves-per-EU model. A cap below the live set forces
// per-iteration scratch spill (645-867 MB WRITE_SIZE observed). Use plain
// bounds for register-hungry kernels; use arg2 only when the live set is
// known to fit (attn streamed softmax fits 128 -> arg2=2 is safe).

__device__ inline __bf16 f2b(float f) {
  __hip_bfloat16 h = __float2bfloat16(f);
  return *reinterpret_cast<__bf16*>(&h);
}
__device__ inline unsigned short b2u(float f) {  // RNE (cold paths)
  __hip_bfloat16 h = __float2bfloat16(f);
  return *reinterpret_cast<unsigned short*>(&h);
}
__device__ inline unsigned short b2u_fast(float f) {  // round-half-up (hot loop)
  union { float f; unsigned u; } v;
  v.f = f;
  return (unsigned short)((v.u + 0x8000u) >> 16);
}
// 16B logical LDS read as two 8B reads (2-way-bank-friendly padded strides)
__device__ inline bf16x8 ld16(const bf16* p) {
  bf16x4 lo = *(const bf16x4*)p;
  bf16x4 hi = *(const bf16x4*)(p + 4);
  return __builtin_shufflevector(lo, hi, 0, 1, 2, 3, 4, 5, 6, 7);
}
__device__ inline void st16(bf16* p, uint4 v) {
  *(uint2*)p = make_uint2(v.x, v.y);
  *(uint2*)(p + 4) = make_uint2(v.z, v.w);
}
__device__ inline us4 shfl32_us4(us4 v) {
  uint2 u = *(uint2*)&v;
  u.x = __shfl_xor(u.x, 32);
  u.y = __shfl_xor(u.y, 32);
  return *(us4*)&u;
}
__device__ inline bf16x8 mk8(us4 lo, us4 hi) {
  bf16x4 l = *(bf16x4*)&lo;
  bf16x4 h = *(bf16x4*)&hi;
  return __builtin_shufflevector(l, h, 0, 1, 2, 3, 4, 5, 6, 7);
}
__device__ inline uint4 cvt8(float4 a0, float4 a1) {
  bf16x8 v;
  v[0] = f2b(a0.x); v[1] = f2b(a0.y); v[2] = f2b(a0.z); v[3] = f2b(a0.w);
  v[4] = f2b(a1.x); v[5] = f2b(a1.y); v[6] = f2b(a1.z); v[7] = f2b(a1.w);
  return *(uint4*)&v;
}

// ---------------- prep: weight transpose+cast (z<3) + T5 bias LUT (z==3) ----------------
__global__ void prep_k(const float* __restrict__ Wq, const float* __restrict__ Wkv,
                       const float* __restrict__ Wo, const float* __restrict__ rel_bias,
                       bf16* __restrict__ WqT, bf16* __restrict__ WkvT,
                       bf16* __restrict__ WoT, float* __restrict__ lut) {
  __shared__ float tile[32][33];
  int z = blockIdx.z;
  int tx = threadIdx.x, ty = threadIdx.y;
  if (z == 3) {  // T5 bias LUT (f64 bucketing = np ref), pre-scaled by log2e
    if (blockIdx.y != 0 || blockIdx.x >= 16) return;
    int r = blockIdx.x * 256 + ty * 32 + tx;
    int rel = r - 2048;
    int bkt = rel > 0 ? 16 : 0;
    int ar = rel < 0 ? -rel : rel;
    int idx;
    if (ar < 8) {
      idx = bkt + ar;
    } else {
      double t = log((double)ar / 8.0) / log(16.0) * 8.0;
      int lg = 8 + (int)t;
      if (lg > 15) lg = 15;
      idx = bkt + lg;
    }
    for (int h = 0; h < 16; ++h)
      lut[h * 4096 + r] = rel_bias[idx * 16 + h] * LOG2E;
    return;
  }
  const float* in = z == 0 ? Wq : (z == 1 ? Wkv : Wo);
  bf16* out = z == 0 ? WqT : (z == 1 ? WkvT : WoT);
  int cols = z == 1 ? 2048 : 1024;
  int c0 = blockIdx.x * 32;
  if (c0 >= cols) return;
  int r0 = blockIdx.y * 32;
  for (int i = ty; i < 32; i += 8)
    tile[i][tx] = in[(size_t)(r0 + i) * cols + c0 + tx];
  __syncthreads();
  for (int i = ty; i < 32; i += 8)
    out[(size_t)(c0 + i) * 1024 + r0 + tx] = __float2bfloat16(tile[tx][i]);
}

// ---------------- fused Q+KV projection GEMM ----------------
// grid (32, 24): y<8 -> Q (x log2e) -> Qb[b,h,s,d]; y>=8: gn<1024 -> Kb[b,h,k,d],
// gn>=1024 -> Vt[b,h,d,k]. Q/K use swapped-operand MFMA (D^T) for packed epilogue.
// A read directly from f32 inputs, cast during staging (no separate cast pass).
// One-step register prefetch (named scalars); PLAIN launch bounds -- the
// (256,3) variant capped VGPR at 84 and spilled the prefetch state (645 MB
// scratch writes, 3x slowdown, rounds 5/6).
#define PS 36
__global__ __launch_bounds__(256) void gemm_qkv_k(const float* __restrict__ hf,
                                                  const float* __restrict__ kvf,
                                                  const bf16* __restrict__ WqT,
                                                  const bf16* __restrict__ WkvT,
                                                  bf16* __restrict__ Qb,
                                                  bf16* __restrict__ Kb,
                                                  bf16* __restrict__ Vt) {
  __shared__ __align__(16) bf16 As[128 * PS];
  __shared__ __align__(16) bf16 Bs[128 * PS];
  const int tid = threadIdx.x;
  const int lane = tid & 63;
  const int w = tid >> 6;
  const int wm = (w >> 1) * 64;
  const int wn = (w & 1) * 64;
  const int l15 = lane & 15;
  const int quad = lane >> 4;
  const int srow = lane >> 2;
  const int skg = lane & 3;

  const bool isQ = blockIdx.y < 8;
  const float* A = isQ ? hf : kvf;
  const bf16* Bt = isQ ? WqT : WkvT;
  const int n0 = (isQ ? blockIdx.y : blockIdx.y - 8) * 128;
  const int m0 = blockIdx.x * 128;
  const bool isV = (!isQ) && (n0 >= 1024);

  f32x4 acc[4][4];
#pragma unroll
  for (int i = 0; i < 4; ++i)
#pragma unroll
    for (int j = 0; j < 4; ++j) acc[i][j] = (f32x4){0.f, 0.f, 0.f, 0.f};

  // per-thread source pointers (seg0 = w*2, seg1 = w*2+1)
  const float* aptr0 = A + (size_t)(m0 + (w * 2) * 16 + srow) * 1024 + skg * 8;
  const float* aptr1 = aptr0 + 16 * 1024;
  const bf16* bptr0 = Bt + (size_t)(n0 + (w * 2) * 16 + srow) * 1024 + skg * 8;
  const bf16* bptr1 = bptr0 + 16 * 1024;
  bf16* awr0 = As + ((w * 2) * 16 + srow) * PS + skg * 8;
  bf16* awr1 = As + ((w * 2 + 1) * 16 + srow) * PS + skg * 8;
  bf16* bwr0 = Bs + ((w * 2) * 16 + srow) * PS + skg * 8;
  bf16* bwr1 = Bs + ((w * 2 + 1) * 16 + srow) * PS + skg * 8;

  // prologue prefetch (named scalars: stays in VGPRs)
  float4 pa0 = *(const float4*)(aptr0);
  float4 pa1 = *(const float4*)(aptr0 + 4);
  float4 pa2 = *(const float4*)(aptr1);
  float4 pa3 = *(const float4*)(aptr1 + 4);
  uint4 pb0 = *(const uint4*)(bptr0);
  uint4 pb1 = *(const uint4*)(bptr1);

  for (int k0 = 0; k0 < 1024; k0 += 32) {
    __syncthreads();  // prev frag reads done
    st16(awr0, cvt8(pa0, pa1));
    st16(awr1, cvt8(pa2, pa3));
    st16(bwr0, pb0);
    st16(bwr1, pb1);
    __syncthreads();
    if (k0 + 32 < 1024) {  // prefetch next step; hides under MFMAs
      int kn = k0 + 32;
      pa0 = *(const float4*)(aptr0 + kn);
      pa1 = *(const float4*)(aptr0 + kn + 4);
      pa2 = *(const float4*)(aptr1 + kn);
      pa3 = *(const float4*)(aptr1 + kn + 4);
      pb0 = *(const uint4*)(bptr0 + kn);
      pb1 = *(const uint4*)(bptr1 + kn);
    }
    bf16x8 af[4], bfr[4];
#pragma unroll
    for (int i = 0; i < 4; ++i)
      af[i] = ld16(As + (wm + i * 16 + l15) * PS + quad * 8);
#pragma unroll
    for (int j = 0; j < 4; ++j)
      bfr[j] = ld16(Bs + (wn + j * 16 + l15) * PS + quad * 8);
    if (isV) {  // normal: lane regs vary gm (=k of V) for packed V^T store
#pragma unroll
      for (int i = 0; i < 4; ++i)
#pragma unroll
        for (int j = 0; j < 4; ++j)
          acc[i][j] = __builtin_amdgcn_mfma_f32_16x16x32_bf16(af[i], bfr[j], acc[i][j], 0, 0, 0);
    } else {  // swapped: D^T, lane regs vary gn (=d) for packed Q/K store
#pragma unroll
      for (int i = 0; i < 4; ++i)
#pragma unroll
        for (int j = 0; j < 4; ++j)
          acc[i][j] = __builtin_amdgcn_mfma_f32_16x16x32_bf16(bfr[j], af[i], acc[i][j], 0, 0, 0);
    }
  }

  if (isV) {  // V -> [b,h,d,k], 4 consecutive k per 8B store
#pragma unroll
    for (int i = 0; i < 4; ++i) {
      int gmb = m0 + wm + i * 16 + quad * 4;
      int b = gmb >> 11, kp = gmb & 2047;
#pragma unroll
      for (int j = 0; j < 4; ++j) {
        int gn = n0 + wn + j * 16 + l15;
        int h = (gn >> 6) & 15, d = gn & 63;
        us4 pk;
#pragma unroll
        for (int r = 0; r < 4; ++r) pk[r] = b2u(acc[i][j][r]);
        *(us4*)(Vt + ((((size_t)b * 16 + h) * 64 + d) << 11) + kp) = pk;
      }
    }
    return;
  }
  // Q/K swapped epilogue: gm = ..+l15 (s), gn = ..+quad*4+r (d packed)
  const float scale = isQ ? LOG2E : 1.0f;
  bf16* dst = isQ ? Qb : Kb;
#pragma unroll
  for (int i = 0; i < 4; ++i) {
    int gm = m0 + wm + i * 16 + l15;
    int b = gm >> 11, s = gm & 2047;
#pragma unroll
    for (int j = 0; j < 4; ++j) {
      int gn = n0 + wn + j * 16 + quad * 4;
      int h = (gn >> 6) & 15, d0 = gn & 63;
      us4 pk;
#pragma unroll
      for (int r = 0; r < 4; ++r) pk[r] = b2u(acc[i][j][r] * scale);
      *(us4*)(dst + ((((size_t)b * 16 + h) * 2048 + s) << 6) + d0) = pk;
    }
  }
}

// ---------------- O projection: out[4096][1024] = Ob * WoT^T, 128x64 tiles ----------------
// Padded-LDS + named-scalar prefetch; PLAIN launch bounds (no VGPR cap).
__global__ __launch_bounds__(256) void gemm_o_k(const bf16* __restrict__ A,
                                                const bf16* __restrict__ Bt,
                                                float* __restrict__ C0) {
  __shared__ __align__(16) bf16 As[128 * PS];
  __shared__ __align__(16) bf16 Bs[64 * PS];
  const int tid = threadIdx.x;
  const int lane = tid & 63;
  const int w = tid >> 6;
  const int wm = w * 32;
  const int m0 = blockIdx.x * 128;
  const int n0 = blockIdx.y * 64;
  const int l15 = lane & 15;
  const int quad = lane >> 4;
  const int srow = lane >> 2;
  const int skg = lane & 3;

  f32x4 acc[2][4];
#pragma unroll
  for (int i = 0; i < 2; ++i)
#pragma unroll
    for (int j = 0; j < 4; ++j) acc[i][j] = (f32x4){0.f, 0.f, 0.f, 0.f};

  const bf16* aptr0 = A + (size_t)(m0 + (w * 2) * 16 + srow) * 1024 + skg * 8;
  const bf16* aptr1 = aptr0 + 16 * 1024;
  const bf16* bptr = Bt + (size_t)(n0 + w * 16 + srow) * 1024 + skg * 8;
  bf16* awr0 = As + ((w * 2) * 16 + srow) * PS + skg * 8;
  bf16* awr1 = As + ((w * 2 + 1) * 16 + srow) * PS + skg * 8;
  bf16* bwr = Bs + (w * 16 + srow) * PS + skg * 8;

  uint4 po0 = *(const uint4*)(aptr0);
  uint4 po1 = *(const uint4*)(aptr1);
  uint4 pbo = *(const uint4*)(bptr);

  for (int k0 = 0; k0 < 1024; k0 += 32) {
    __syncthreads();
    st16(awr0, po0);
    st16(awr1, po1);
    st16(bwr, pbo);
    __syncthreads();
    if (k0 + 32 < 1024) {
      int kn = k0 + 32;
      po0 = *(const uint4*)(aptr0 + kn);
      po1 = *(const uint4*)(aptr1 + kn);
      pbo = *(const uint4*)(bptr + kn);
    }
    bf16x8 af[2], bfr[4];
#pragma unroll
    for (int i = 0; i < 2; ++i)
      af[i] = ld16(As + (wm + i * 16 + l15) * PS + quad * 8);
#pragma unroll
    for (int j = 0; j < 4; ++j)
      bfr[j] = ld16(Bs + (j * 16 + l15) * PS + quad * 8);
#pragma unroll
    for (int i = 0; i < 2; ++i)
#pragma unroll
      for (int j = 0; j < 4; ++j)
        acc[i][j] = __builtin_amdgcn_mfma_f32_16x16x32_bf16(bfr[j], af[i], acc[i][j], 0, 0, 0);
  }
#pragma unroll
  for (int i = 0; i < 2; ++i) {
    int gm = m0 + wm + i * 16 + l15;
#pragma unroll
    for (int j = 0; j < 4; ++j) {
      int gn = n0 + j * 16 + quad * 4;
      *(f32x4*)(C0 + (size_t)gm * 1024 + gn) = acc[i][j];
    }
  }
}

// ---------------- fused attention, transposed-S, streamed softmax, NO max tracking ----------------
// 8 waves / 512 threads: waves 0-3 (kg=0) process even 128-k tiles, waves 4-7
// (kg=1) odd tiles, each group with private Ks/Vs LDS buffer. Wave wq owns
// q-strip [qb+wq*32,+32); lane owns one q (col=lane&31).
// Softmax uses FIXED m=0 (scores bounded ~|25| by construction; exact softmax
// for any consistent m). End: group 1 dumps (l,O) to LDS; group 0 merges.
// LDS: lbias[2176]f32 | Ks[2][128*STK] | Vs[2][64*SVK] = 78336 B (2 blocks/CU).
// launch_bounds arg2=2 -> VGPR cap 128 (toolchain: cap = 256/arg2). LDS caps
// residency at 2 blocks/CU = 4 waves/SIMD; 4x128 = 512 regs/SIMD fits exactly,
// so the wider cap costs no occupancy but gives the allocator slack.
#define STK 68
#define SVK 136
#define KS_OFF 8704
#define VS_OFF 43520
__global__ __launch_bounds__(512, 2) void attn_k(const bf16* __restrict__ Qb,
                                                 const bf16* __restrict__ Kb,
                                                 const bf16* __restrict__ Vt,
                                                 const float* __restrict__ lut,
                                                 bf16* __restrict__ Ob) {
  __shared__ __align__(16) char smem[78336];
  float* lbias = (float*)smem;
  bf16* Ksb = (bf16*)(smem + KS_OFF);  // [2][128*STK]
  bf16* Vsb = (bf16*)(smem + VS_OFF);  // [2][64*SVK]

  const int tid = threadIdx.x;
  const int lane = tid & 63;
  const int w = tid >> 6;    // 0..7
  const int wq = w & 3;      // q-strip within block
  const int kg = w >> 2;     // k-group: 0 = even tiles, 1 = odd tiles
  const int t256 = tid & 255;
  const int q31 = lane & 31;
  const int half = lane >> 5;

  bf16* Ks = Ksb + kg * (128 * STK);
  bf16* Vs = Vsb + kg * (64 * SVK);

  const int qt = blockIdx.x;  // 0..15
  const int bh = blockIdx.y;  // 0..31
  const int h = bh & 15, b = bh >> 4;
  const int qb = qt * 128;

  const int gbase = h * 4096 + 1921 - qb;
  for (int t = tid; t < 2175; t += 512) lbias[t] = lut[gbase + t];

  const size_t base = (size_t)bh * 2048 * 64;   // Qb/Kb rows
  const size_t vbase = (size_t)bh * 64 * 2048;  // Vt rows
  const int qg = qb + wq * 32 + q31;

  // Q B-frags (pre-scaled by log2e in projection)
  bf16x8 qf[4];
#pragma unroll
  for (int c = 0; c < 4; ++c)
    qf[c] = *(const bf16x8*)(Qb + base + (size_t)qg * 64 + c * 16 + half * 8);

  f32x16 oacc[2];
#pragma unroll
  for (int dj = 0; dj < 2; ++dj)
#pragma unroll
    for (int r = 0; r < 16; ++r) oacc[dj][r] = 0.f;
  float l_run = 0.f;

  const int kt0 = kg * 128;  // group's first tile

  for (int it = 0; it < 8; ++it) {
    const int kt = it * 256 + kt0;  // this group's k-tile base
    __syncthreads();  // all waves done reading their Ks/Vs
    {  // stage: issue both K and V loads, one wait, write LDS (no cross-tile regs)
      uint4 kr[4], vr[4];
#pragma unroll
      for (int rep = 0; rep < 4; ++rep) {
        int slot = t256 + rep * 256;
        kr[rep] = *(const uint4*)(Kb + base + (size_t)(kt + (slot >> 3)) * 64 + (slot & 7) * 8);
        vr[rep] = *(const uint4*)(Vt + vbase + (size_t)(slot >> 4) * 2048 + kt + (slot & 15) * 8);
      }
#pragma unroll
      for (int rep = 0; rep < 4; ++rep) {
        int slot = t256 + rep * 256;
        st16(Ks + (slot >> 3) * STK + (slot & 7) * 8, kr[rep]);
        st16(Vs + (slot >> 4) * SVK + (slot & 15) * 8, vr[rep]);
      }
    }
    __syncthreads();

    const int xbase = kt + 127 + 4 * half - wq * 32 - q31;
#pragma unroll
    for (int mt = 0; mt < 4; ++mt) {
      // S^T = K·Q^T for this 32-k mt-tile; bias pre-loaded in the accumulator
      f32x16 sacc;
#pragma unroll
      for (int a2 = 0; a2 < 4; ++a2)
#pragma unroll
        for (int rr = 0; rr < 4; ++rr)
          sacc[4 * a2 + rr] = lbias[xbase + mt * 32 + 8 * a2 + rr];
#pragma unroll
      for (int c = 0; c < 4; ++c) {
        bf16x8 kf = ld16(Ks + (mt * 32 + q31) * STK + c * 16 + half * 8);
        sacc = __builtin_amdgcn_mfma_f32_32x32x16_bf16(kf, qf[c], sacc, 0, 0, 0);
      }

      // exp (m=0, no subtract) + sum (4 parallel accumulators) + pack quads
      us4 ownq[4];
      f32x4 sv = (f32x4){0.f, 0.f, 0.f, 0.f};
#pragma unroll
      for (int a = 0; a < 4; ++a) {
        us4 pk;
#pragma unroll
        for (int rr = 0; rr < 4; ++rr) {
          float p = EXP2(sacc[4 * a + rr]);
          sv[rr] += p;
          pk[rr] = b2u_fast(p);
        }
        ownq[a] = pk;
      }
      l_run += (sv[0] + sv[1]) + (sv[2] + sv[3]);

      // exchange complementary k-quads across the half boundary (no LDS)
      us4 rcv0 = shfl32_us4(half ? ownq[0] : ownq[1]);
      us4 rcv1 = shfl32_us4(half ? ownq[2] : ownq[3]);

      // O^T += V^T·P^T for this mt's two 16-k chunks
#pragma unroll
      for (int p = 0; p < 2; ++p) {
        us4 rc = p ? rcv1 : rcv0;
        bf16x8 pfc = half ? mk8(rc, ownq[2 * p + 1]) : mk8(ownq[2 * p], rc);
#pragma unroll
        for (int dj = 0; dj < 2; ++dj) {
          bf16x8 vf = ld16(Vs + (dj * 32 + q31) * SVK + (mt * 2 + p) * 16 + half * 8);
          oacc[dj] = __builtin_amdgcn_mfma_f32_32x32x16_bf16(vf, pfc, oacc[dj], 0, 0, 0);
        }
      }
    }
  }

  // pair-sum of l (one shfl at the end)
  l_run += __shfl_xor(l_run, 32);

  // ---- merge the two k-groups (group 1 -> LDS -> group 0 combines) ----
  __syncthreads();  // everyone done with Ks/Vs/lbias
  float* mbuf = (float*)smem;  // 4 waves * 64 lanes * 35 f32 = 35840 B (< 78336)
  if (kg) {
    float* p = mbuf + ((size_t)(wq * 64 + lane)) * 35;  // stride 35: 2-way banks, free
    p[0] = l_run;
#pragma unroll
    for (int dj = 0; dj < 2; ++dj)
#pragma unroll
      for (int r = 0; r < 16; ++r) p[1 + dj * 16 + r] = oacc[dj][r];
  }
  __syncthreads();
  if (kg) return;

  const float* p = mbuf + ((size_t)(wq * 64 + lane)) * 35;
  float inv = 1.0f / (l_run + p[0]);

  // epilogue: O[qg][d] = (O0+O1)/(l0+l1), 8B packed stores
#pragma unroll
  for (int dj = 0; dj < 2; ++dj)
#pragma unroll
    for (int g = 0; g < 4; ++g) {
      us4 pk;
#pragma unroll
      for (int rr = 0; rr < 4; ++rr)
        pk[rr] = b2u((oacc[dj][4 * g + rr] + p[1 + dj * 16 + 4 * g + rr]) * inv);
      int d0 = dj * 32 + 8 * g + 4 * half;
      *(us4*)(Ob + ((size_t)(b * 2048 + qg)) * 1024 + h * 64 + d0) = pk;
    }
}

// ---------------- launch ----------------
extern "C" void kernel_launch(void* const* d_in, const int* in_sizes, int n_in,
                              void* d_out, int out_size, void* d_ws, size_t ws_size,
                              hipStream_t stream) {
  const float* hidden = (const float*)d_in[0];
  const float* kvs    = (const float*)d_in[1];
  const float* Wq     = (const float*)d_in[2];
  const float* Wkv    = (const float*)d_in[3];
  const float* Wo     = (const float*)d_in[4];
  const float* relb   = (const float*)d_in[5];
  float* out = (float*)d_out;

  char* ws = (char*)d_ws;
  bf16* WqT  = (bf16*)(ws + (size_t)0);           // 2 MB
  bf16* WkvT = (bf16*)(ws + ((size_t)2 << 20));   // 4 MB
  bf16* WoT  = (bf16*)(ws + ((size_t)6 << 20));   // 2 MB
  bf16* Ob   = (bf16*)(ws + ((size_t)8 << 20));   // 8 MB [B,S,E]
  bf16* Qb   = (bf16*)(ws + ((size_t)16 << 20));  // 8 MB [B,H,S,D]
  bf16* Kb   = (bf16*)(ws + ((size_t)24 << 20));  // 8 MB [B,H,K,D]
  bf16* Vt   = (bf16*)(ws + ((size_t)32 << 20));  // 8 MB [B,H,D,K]
  float* LUT = (float*)(ws + ((size_t)40 << 20)); // 256 KB

  // weights transpose+cast + bias LUT, one launch
  prep_k<<<dim3(64, 32, 4), dim3(32, 8), 0, stream>>>(Wq, Wkv, Wo, relb, WqT, WkvT, WoT, LUT);
  // Q (x log2e), K, V projections — reads f32 inputs directly (cast fused)
  gemm_qkv_k<<<dim3(32, 24), 256, 0, stream>>>(hidden, kvs, WqT, WkvT, Qb, Kb, Vt);
  // attention -> Ob
  attn_k<<<dim3(16, 32), 512, 0, stream>>>(Qb, Kb, Vt, LUT, Ob);
  // out = Ob @ Wo
  gemm_o_k<<<dim3(32, 16), 256, 0, stream>>>(Ob, WoT, out);
}

// Round 8
// 221.522 us; speedup vs baseline: 2.0783x; 1.0080x over previous
//
#include <hip/hip_runtime.h>
#include <hip/hip_bf16.h>
#include <math.h>

typedef __hip_bfloat16 bf16;
typedef __bf16 bf16x4 __attribute__((ext_vector_type(4)));
typedef __bf16 bf16x8 __attribute__((ext_vector_type(8)));
typedef float f32x4 __attribute__((ext_vector_type(4)));
typedef float f32x16 __attribute__((ext_vector_type(16)));
typedef unsigned short us4 __attribute__((ext_vector_type(4)));

#define LOG2E 1.44269504088896340736f

#if defined(__has_builtin)
#if __has_builtin(__builtin_amdgcn_exp2f)
#define EXP2(x) __builtin_amdgcn_exp2f(x)
#else
#define EXP2(x) exp2f(x)
#endif
#else
#define EXP2(x) exp2f(x)
#endif

// NOTE on __launch_bounds__ (measured on this toolchain, rounds 2/4/5/6/7):
// the 2nd arg caps VGPRs at ~256/arg2 (arg2=4 -> 64, arg2=3 -> 84), NOT the
// waves-per-EU model. A cap below the live set forces per-iteration scratch
// spill (645-867 MB WRITE_SIZE observed). Plain bounds for register-hungry
// kernels; arg2 only when the live set provably fits.

__device__ inline __bf16 f2b(float f) {
  __hip_bfloat16 h = __float2bfloat16(f);
  return *reinterpret_cast<__bf16*>(&h);
}
__device__ inline unsigned short b2u(float f) {  // RNE (cold paths)
  __hip_bfloat16 h = __float2bfloat16(f);
  return *reinterpret_cast<unsigned short*>(&h);
}
__device__ inline unsigned short b2u_fast(float f) {  // round-half-up (hot loop)
  union { float f; unsigned u; } v;
  v.f = f;
  return (unsigned short)((v.u + 0x8000u) >> 16);
}
// 16B logical LDS read as two 8B reads
__device__ inline bf16x8 ld16(const bf16* p) {
  bf16x4 lo = *(const bf16x4*)p;
  bf16x4 hi = *(const bf16x4*)(p + 4);
  return __builtin_shufflevector(lo, hi, 0, 1, 2, 3, 4, 5, 6, 7);
}
__device__ inline void st16(bf16* p, uint4 v) {
  *(uint2*)p = make_uint2(v.x, v.y);
  *(uint2*)(p + 4) = make_uint2(v.z, v.w);
}
__device__ inline us4 shfl32_us4(us4 v) {
  uint2 u = *(uint2*)&v;
  u.x = __shfl_xor(u.x, 32);
  u.y = __shfl_xor(u.y, 32);
  return *(us4*)&u;
}
__device__ inline bf16x8 mk8(us4 lo, us4 hi) {
  bf16x4 l = *(bf16x4*)&lo;
  bf16x4 h = *(bf16x4*)&hi;
  return __builtin_shufflevector(l, h, 0, 1, 2, 3, 4, 5, 6, 7);
}
__device__ inline uint4 cvt8(float4 a0, float4 a1) {
  bf16x8 v;
  v[0] = f2b(a0.x); v[1] = f2b(a0.y); v[2] = f2b(a0.z); v[3] = f2b(a0.w);
  v[4] = f2b(a1.x); v[5] = f2b(a1.y); v[6] = f2b(a1.z); v[7] = f2b(a1.w);
  return *(uint4*)&v;
}

// ---------------- prep: weight transpose+cast (z<3) + T5 bias LUT (z==3) ----------------
__global__ void prep_k(const float* __restrict__ Wq, const float* __restrict__ Wkv,
                       const float* __restrict__ Wo, const float* __restrict__ rel_bias,
                       bf16* __restrict__ WqT, bf16* __restrict__ WkvT,
                       bf16* __restrict__ WoT, float* __restrict__ lut) {
  __shared__ float tile[32][33];
  int z = blockIdx.z;
  int tx = threadIdx.x, ty = threadIdx.y;
  if (z == 3) {  // T5 bias LUT (f64 bucketing = np ref), pre-scaled by log2e
    if (blockIdx.y != 0 || blockIdx.x >= 16) return;
    int r = blockIdx.x * 256 + ty * 32 + tx;
    int rel = r - 2048;
    int bkt = rel > 0 ? 16 : 0;
    int ar = rel < 0 ? -rel : rel;
    int idx;
    if (ar < 8) {
      idx = bkt + ar;
    } else {
      double t = log((double)ar / 8.0) / log(16.0) * 8.0;
      int lg = 8 + (int)t;
      if (lg > 15) lg = 15;
      idx = bkt + lg;
    }
    for (int h = 0; h < 16; ++h)
      lut[h * 4096 + r] = rel_bias[idx * 16 + h] * LOG2E;
    return;
  }
  const float* in = z == 0 ? Wq : (z == 1 ? Wkv : Wo);
  bf16* out = z == 0 ? WqT : (z == 1 ? WkvT : WoT);
  int cols = z == 1 ? 2048 : 1024;
  int c0 = blockIdx.x * 32;
  if (c0 >= cols) return;
  int r0 = blockIdx.y * 32;
  for (int i = ty; i < 32; i += 8)
    tile[i][tx] = in[(size_t)(r0 + i) * cols + c0 + tx];
  __syncthreads();
  for (int i = ty; i < 32; i += 8)
    out[(size_t)(c0 + i) * 1024 + r0 + tx] = __float2bfloat16(tile[tx][i]);
}

// ---------------- fused Q+KV projection GEMM, 2-deep pipelined ----------------
// grid (32, 24): y<8 -> Q (x log2e) -> Qb[b,h,s,d]; y>=8: gn<1024 -> Kb[b,h,k,d],
// gn>=1024 -> Vt[b,h,d,k]. Q/K use swapped-operand MFMA (D^T) for packed epilogue.
// A read from f32 inputs, cast during staging. TWO named prefetch register
// sets + 2x-unrolled loop: load-to-use distance = one full k-iteration
// (~600-1200 cyc), matching L2/HBM latency that round-7's 1-deep pipeline
// left exposed (measured 1750 cyc/step, MfmaUtil 14%).
#define PS 36
__global__ __launch_bounds__(256) void gemm_qkv_k(const float* __restrict__ hf,
                                                  const float* __restrict__ kvf,
                                                  const bf16* __restrict__ WqT,
                                                  const bf16* __restrict__ WkvT,
                                                  bf16* __restrict__ Qb,
                                                  bf16* __restrict__ Kb,
                                                  bf16* __restrict__ Vt) {
  __shared__ __align__(16) bf16 As[128 * PS];
  __shared__ __align__(16) bf16 Bs[128 * PS];
  const int tid = threadIdx.x;
  const int lane = tid & 63;
  const int w = tid >> 6;
  const int wm = (w >> 1) * 64;
  const int wn = (w & 1) * 64;
  const int l15 = lane & 15;
  const int quad = lane >> 4;
  const int srow = lane >> 2;
  const int skg = lane & 3;

  const bool isQ = blockIdx.y < 8;
  const float* A = isQ ? hf : kvf;
  const bf16* Bt = isQ ? WqT : WkvT;
  const int n0 = (isQ ? blockIdx.y : blockIdx.y - 8) * 128;
  const int m0 = blockIdx.x * 128;
  const bool isV = (!isQ) && (n0 >= 1024);

  f32x4 acc[4][4];
#pragma unroll
  for (int i = 0; i < 4; ++i)
#pragma unroll
    for (int j = 0; j < 4; ++j) acc[i][j] = (f32x4){0.f, 0.f, 0.f, 0.f};

  const float* aptr0 = A + (size_t)(m0 + (w * 2) * 16 + srow) * 1024 + skg * 8;
  const float* aptr1 = aptr0 + 16 * 1024;
  const bf16* bptr0 = Bt + (size_t)(n0 + (w * 2) * 16 + srow) * 1024 + skg * 8;
  const bf16* bptr1 = bptr0 + 16 * 1024;
  bf16* awr0 = As + ((w * 2) * 16 + srow) * PS + skg * 8;
  bf16* awr1 = As + ((w * 2 + 1) * 16 + srow) * PS + skg * 8;
  bf16* bwr0 = Bs + ((w * 2) * 16 + srow) * PS + skg * 8;
  bf16* bwr1 = Bs + ((w * 2 + 1) * 16 + srow) * PS + skg * 8;

  // two named prefetch sets (NOT arrays -- scratch trap)
  float4 a00, a01, a02, a03, a10, a11, a12, a13;
  uint4 b00, b01, b10, b11;
  // prologue: set0 <- tile k=0, set1 <- tile k=32
  a00 = *(const float4*)(aptr0);       a01 = *(const float4*)(aptr0 + 4);
  a02 = *(const float4*)(aptr1);       a03 = *(const float4*)(aptr1 + 4);
  b00 = *(const uint4*)(bptr0);        b01 = *(const uint4*)(bptr1);
  a10 = *(const float4*)(aptr0 + 32);  a11 = *(const float4*)(aptr0 + 36);
  a12 = *(const float4*)(aptr1 + 32);  a13 = *(const float4*)(aptr1 + 36);
  b10 = *(const uint4*)(bptr0 + 32);   b11 = *(const uint4*)(bptr1 + 32);

#define QKV_COMPUTE()                                                          \
  do {                                                                         \
    bf16x8 af[4], bfr[4];                                                      \
    _Pragma("unroll") for (int i = 0; i < 4; ++i)                              \
        af[i] = ld16(As + (wm + i * 16 + l15) * PS + quad * 8);                \
    _Pragma("unroll") for (int j = 0; j < 4; ++j)                              \
        bfr[j] = ld16(Bs + (wn + j * 16 + l15) * PS + quad * 8);               \
    if (isV) {                                                                 \
      _Pragma("unroll") for (int i = 0; i < 4; ++i)                            \
          _Pragma("unroll") for (int j = 0; j < 4; ++j)                        \
          acc[i][j] =                                                          \
              __builtin_amdgcn_mfma_f32_16x16x32_bf16(af[i], bfr[j],           \
                                                      acc[i][j], 0, 0, 0);     \
    } else {                                                                   \
      _Pragma("unroll") for (int i = 0; i < 4; ++i)                            \
          _Pragma("unroll") for (int j = 0; j < 4; ++j)                        \
          acc[i][j] =                                                          \
              __builtin_amdgcn_mfma_f32_16x16x32_bf16(bfr[j], af[i],           \
                                                      acc[i][j], 0, 0, 0);     \
    }                                                                          \
  } while (0)

  for (int k0 = 0; k0 < 1024; k0 += 64) {
    // ---- sub-step A: stage tile k0 (set0), refill set0 from k0+64
    __syncthreads();
    st16(awr0, cvt8(a00, a01));
    st16(awr1, cvt8(a02, a03));
    st16(bwr0, b00);
    st16(bwr1, b01);
    __syncthreads();
    if (k0 + 64 < 1024) {
      int kn = k0 + 64;
      a00 = *(const float4*)(aptr0 + kn);     a01 = *(const float4*)(aptr0 + kn + 4);
      a02 = *(const float4*)(aptr1 + kn);     a03 = *(const float4*)(aptr1 + kn + 4);
      b00 = *(const uint4*)(bptr0 + kn);      b01 = *(const uint4*)(bptr1 + kn);
    }
    QKV_COMPUTE();
    // ---- sub-step B: stage tile k0+32 (set1), refill set1 from k0+96
    __syncthreads();
    st16(awr0, cvt8(a10, a11));
    st16(awr1, cvt8(a12, a13));
    st16(bwr0, b10);
    st16(bwr1, b11);
    __syncthreads();
    if (k0 + 96 < 1024) {
      int kn = k0 + 96;
      a10 = *(const float4*)(aptr0 + kn);     a11 = *(const float4*)(aptr0 + kn + 4);
      a12 = *(const float4*)(aptr1 + kn);     a13 = *(const float4*)(aptr1 + kn + 4);
      b10 = *(const uint4*)(bptr0 + kn);      b11 = *(const uint4*)(bptr1 + kn);
    }
    QKV_COMPUTE();
  }
#undef QKV_COMPUTE

  if (isV) {  // V -> [b,h,d,k], 4 consecutive k per 8B store
#pragma unroll
    for (int i = 0; i < 4; ++i) {
      int gmb = m0 + wm + i * 16 + quad * 4;
      int b = gmb >> 11, kp = gmb & 2047;
#pragma unroll
      for (int j = 0; j < 4; ++j) {
        int gn = n0 + wn + j * 16 + l15;
        int h = (gn >> 6) & 15, d = gn & 63;
        us4 pk;
#pragma unroll
        for (int r = 0; r < 4; ++r) pk[r] = b2u(acc[i][j][r]);
        *(us4*)(Vt + ((((size_t)b * 16 + h) * 64 + d) << 11) + kp) = pk;
      }
    }
    return;
  }
  // Q/K swapped epilogue: gm = ..+l15 (s), gn = ..+quad*4+r (d packed)
  const float scale = isQ ? LOG2E : 1.0f;
  bf16* dst = isQ ? Qb : Kb;
#pragma unroll
  for (int i = 0; i < 4; ++i) {
    int gm = m0 + wm + i * 16 + l15;
    int b = gm >> 11, s = gm & 2047;
#pragma unroll
    for (int j = 0; j < 4; ++j) {
      int gn = n0 + wn + j * 16 + quad * 4;
      int h = (gn >> 6) & 15, d0 = gn & 63;
      us4 pk;
#pragma unroll
      for (int r = 0; r < 4; ++r) pk[r] = b2u(acc[i][j][r] * scale);
      *(us4*)(dst + ((((size_t)b * 16 + h) * 2048 + s) << 6) + d0) = pk;
    }
  }
}

// ---------------- O projection: out[4096][1024] = Ob * WoT^T, 128x64 tiles ----------------
// Same 2-deep pipeline; swapped-operand MFMA -> float4 stores
__global__ __launch_bounds__(256) void gemm_o_k(const bf16* __restrict__ A,
                                                const bf16* __restrict__ Bt,
                                                float* __restrict__ C0) {
  __shared__ __align__(16) bf16 As[128 * PS];
  __shared__ __align__(16) bf16 Bs[64 * PS];
  const int tid = threadIdx.x;
  const int lane = tid & 63;
  const int w = tid >> 6;
  const int wm = w * 32;
  const int m0 = blockIdx.x * 128;
  const int n0 = blockIdx.y * 64;
  const int l15 = lane & 15;
  const int quad = lane >> 4;
  const int srow = lane >> 2;
  const int skg = lane & 3;

  f32x4 acc[2][4];
#pragma unroll
  for (int i = 0; i < 2; ++i)
#pragma unroll
    for (int j = 0; j < 4; ++j) acc[i][j] = (f32x4){0.f, 0.f, 0.f, 0.f};

  const bf16* aptr0 = A + (size_t)(m0 + (w * 2) * 16 + srow) * 1024 + skg * 8;
  const bf16* aptr1 = aptr0 + 16 * 1024;
  const bf16* bptr = Bt + (size_t)(n0 + w * 16 + srow) * 1024 + skg * 8;
  bf16* awr0 = As + ((w * 2) * 16 + srow) * PS + skg * 8;
  bf16* awr1 = As + ((w * 2 + 1) * 16 + srow) * PS + skg * 8;
  bf16* bwr = Bs + (w * 16 + srow) * PS + skg * 8;

  uint4 p00, p01, pb0, p10, p11, pb1;
  p00 = *(const uint4*)(aptr0);       p01 = *(const uint4*)(aptr1);
  pb0 = *(const uint4*)(bptr);
  p10 = *(const uint4*)(aptr0 + 32);  p11 = *(const uint4*)(aptr1 + 32);
  pb1 = *(const uint4*)(bptr + 32);

#define O_COMPUTE()                                                            \
  do {                                                                         \
    bf16x8 af[2], bfr[4];                                                      \
    _Pragma("unroll") for (int i = 0; i < 2; ++i)                              \
        af[i] = ld16(As + (wm + i * 16 + l15) * PS + quad * 8);                \
    _Pragma("unroll") for (int j = 0; j < 4; ++j)                              \
        bfr[j] = ld16(Bs + (j * 16 + l15) * PS + quad * 8);                    \
    _Pragma("unroll") for (int i = 0; i < 2; ++i)                              \
        _Pragma("unroll") for (int j = 0; j < 4; ++j)                          \
        acc[i][j] = __builtin_amdgcn_mfma_f32_16x16x32_bf16(bfr[j], af[i],     \
                                                            acc[i][j], 0, 0, 0); \
  } while (0)

  for (int k0 = 0; k0 < 1024; k0 += 64) {
    __syncthreads();
    st16(awr0, p00);
    st16(awr1, p01);
    st16(bwr, pb0);
    __syncthreads();
    if (k0 + 64 < 1024) {
      int kn = k0 + 64;
      p00 = *(const uint4*)(aptr0 + kn);
      p01 = *(const uint4*)(aptr1 + kn);
      pb0 = *(const uint4*)(bptr + kn);
    }
    O_COMPUTE();
    __syncthreads();
    st16(awr0, p10);
    st16(awr1, p11);
    st16(bwr, pb1);
    __syncthreads();
    if (k0 + 96 < 1024) {
      int kn = k0 + 96;
      p10 = *(const uint4*)(aptr0 + kn);
      p11 = *(const uint4*)(aptr1 + kn);
      pb1 = *(const uint4*)(bptr + kn);
    }
    O_COMPUTE();
  }
#undef O_COMPUTE

#pragma unroll
  for (int i = 0; i < 2; ++i) {
    int gm = m0 + wm + i * 16 + l15;
#pragma unroll
    for (int j = 0; j < 4; ++j) {
      int gn = n0 + j * 16 + quad * 4;
      *(f32x4*)(C0 + (size_t)gm * 1024 + gn) = acc[i][j];
    }
  }
}

// ---------------- fused attention, transposed-S, streamed softmax, NO max tracking ----------------
// 8 waves / 512 threads: waves 0-3 (kg=0) process even 128-k tiles, waves 4-7
// (kg=1) odd tiles, each group with private Ks/Vs LDS buffer. Wave wq owns
// q-strip [qb+wq*32,+32); lane owns one q (col=lane&31).
// Softmax uses FIXED m=0 (scores bounded ~|25| by construction; exact softmax
// for any consistent m). End: group 1 dumps (l,O) to LDS; group 0 merges.
// LDS: lbias[2176]f32 | Ks[2][128*STK] | Vs[2][64*SVK] = 78336 B (2 blocks/CU).
// arg2=2 -> VGPR cap 128; streamed-softmax live set fits, and LDS caps
// residency at 2 blocks/CU anyway, so the cap costs no occupancy.
#define STK 68
#define SVK 136
#define KS_OFF 8704
#define VS_OFF 43520
__global__ __launch_bounds__(512, 2) void attn_k(const bf16* __restrict__ Qb,
                                                 const bf16* __restrict__ Kb,
                                                 const bf16* __restrict__ Vt,
                                                 const float* __restrict__ lut,
                                                 bf16* __restrict__ Ob) {
  __shared__ __align__(16) char smem[78336];
  float* lbias = (float*)smem;
  bf16* Ksb = (bf16*)(smem + KS_OFF);  // [2][128*STK]
  bf16* Vsb = (bf16*)(smem + VS_OFF);  // [2][64*SVK]

  const int tid = threadIdx.x;
  const int lane = tid & 63;
  const int w = tid >> 6;    // 0..7
  const int wq = w & 3;      // q-strip within block
  const int kg = w >> 2;     // k-group: 0 = even tiles, 1 = odd tiles
  const int t256 = tid & 255;
  const int q31 = lane & 31;
  const int half = lane >> 5;

  bf16* Ks = Ksb + kg * (128 * STK);
  bf16* Vs = Vsb + kg * (64 * SVK);

  const int qt = blockIdx.x;  // 0..15
  const int bh = blockIdx.y;  // 0..31
  const int h = bh & 15, b = bh >> 4;
  const int qb = qt * 128;

  const int gbase = h * 4096 + 1921 - qb;
  for (int t = tid; t < 2175; t += 512) lbias[t] = lut[gbase + t];

  const size_t base = (size_t)bh * 2048 * 64;   // Qb/Kb rows
  const size_t vbase = (size_t)bh * 64 * 2048;  // Vt rows
  const int qg = qb + wq * 32 + q31;

  // Q B-frags (pre-scaled by log2e in projection)
  bf16x8 qf[4];
#pragma unroll
  for (int c = 0; c < 4; ++c)
    qf[c] = *(const bf16x8*)(Qb + base + (size_t)qg * 64 + c * 16 + half * 8);

  f32x16 oacc[2];
#pragma unroll
  for (int dj = 0; dj < 2; ++dj)
#pragma unroll
    for (int r = 0; r < 16; ++r) oacc[dj][r] = 0.f;
  float l_run = 0.f;

  const int kt0 = kg * 128;  // group's first tile

  for (int it = 0; it < 8; ++it) {
    const int kt = it * 256 + kt0;  // this group's k-tile base
    __syncthreads();  // all waves done reading their Ks/Vs
    {  // stage: issue both K and V loads, one wait, write LDS (no cross-tile regs)
      uint4 kr[4], vr[4];
#pragma unroll
      for (int rep = 0; rep < 4; ++rep) {
        int slot = t256 + rep * 256;
        kr[rep] = *(const uint4*)(Kb + base + (size_t)(kt + (slot >> 3)) * 64 + (slot & 7) * 8);
        vr[rep] = *(const uint4*)(Vt + vbase + (size_t)(slot >> 4) * 2048 + kt + (slot & 15) * 8);
      }
#pragma unroll
      for (int rep = 0; rep < 4; ++rep) {
        int slot = t256 + rep * 256;
        st16(Ks + (slot >> 3) * STK + (slot & 7) * 8, kr[rep]);
        st16(Vs + (slot >> 4) * SVK + (slot & 15) * 8, vr[rep]);
      }
    }
    __syncthreads();

    const int xbase = kt + 127 + 4 * half - wq * 32 - q31;
#pragma unroll
    for (int mt = 0; mt < 4; ++mt) {
      // S^T = K·Q^T for this 32-k mt-tile; bias pre-loaded in the accumulator
      f32x16 sacc;
#pragma unroll
      for (int a2 = 0; a2 < 4; ++a2)
#pragma unroll
        for (int rr = 0; rr < 4; ++rr)
          sacc[4 * a2 + rr] = lbias[xbase + mt * 32 + 8 * a2 + rr];
#pragma unroll
      for (int c = 0; c < 4; ++c) {
        bf16x8 kf = ld16(Ks + (mt * 32 + q31) * STK + c * 16 + half * 8);
        sacc = __builtin_amdgcn_mfma_f32_32x32x16_bf16(kf, qf[c], sacc, 0, 0, 0);
      }

      // exp (m=0, no subtract) + sum (4 parallel accumulators) + pack quads
      us4 ownq[4];
      f32x4 sv = (f32x4){0.f, 0.f, 0.f, 0.f};
#pragma unroll
      for (int a = 0; a < 4; ++a) {
        us4 pk;
#pragma unroll
        for (int rr = 0; rr < 4; ++rr) {
          float p = EXP2(sacc[4 * a + rr]);
          sv[rr] += p;
          pk[rr] = b2u_fast(p);
        }
        ownq[a] = pk;
      }
      l_run += (sv[0] + sv[1]) + (sv[2] + sv[3]);

      // exchange complementary k-quads across the half boundary (no LDS)
      us4 rcv0 = shfl32_us4(half ? ownq[0] : ownq[1]);
      us4 rcv1 = shfl32_us4(half ? ownq[2] : ownq[3]);

      // O^T += V^T·P^T for this mt's two 16-k chunks
#pragma unroll
      for (int p = 0; p < 2; ++p) {
        us4 rc = p ? rcv1 : rcv0;
        bf16x8 pfc = half ? mk8(rc, ownq[2 * p + 1]) : mk8(ownq[2 * p], rc);
#pragma unroll
        for (int dj = 0; dj < 2; ++dj) {
          bf16x8 vf = ld16(Vs + (dj * 32 + q31) * SVK + (mt * 2 + p) * 16 + half * 8);
          oacc[dj] = __builtin_amdgcn_mfma_f32_32x32x16_bf16(vf, pfc, oacc[dj], 0, 0, 0);
        }
      }
    }
  }

  // pair-sum of l (one shfl at the end)
  l_run += __shfl_xor(l_run, 32);

  // ---- merge the two k-groups (group 1 -> LDS -> group 0 combines) ----
  __syncthreads();  // everyone done with Ks/Vs/lbias
  float* mbuf = (float*)smem;  // 4 waves * 64 lanes * 35 f32 = 35840 B (< 78336)
  if (kg) {
    float* p = mbuf + ((size_t)(wq * 64 + lane)) * 35;  // stride 35: 2-way banks, free
    p[0] = l_run;
#pragma unroll
    for (int dj = 0; dj < 2; ++dj)
#pragma unroll
      for (int r = 0; r < 16; ++r) p[1 + dj * 16 + r] = oacc[dj][r];
  }
  __syncthreads();
  if (kg) return;

  const float* p = mbuf + ((size_t)(wq * 64 + lane)) * 35;
  float inv = 1.0f / (l_run + p[0]);

  // epilogue: O[qg][d] = (O0+O1)/(l0+l1), 8B packed stores
#pragma unroll
  for (int dj = 0; dj < 2; ++dj)
#pragma unroll
    for (int g = 0; g < 4; ++g) {
      us4 pk;
#pragma unroll
      for (int rr = 0; rr < 4; ++rr)
        pk[rr] = b2u((oacc[dj][4 * g + rr] + p[1 + dj * 16 + 4 * g + rr]) * inv);
      int d0 = dj * 32 + 8 * g + 4 * half;
      *(us4*)(Ob + ((size_t)(b * 2048 + qg)) * 1024 + h * 64 + d0) = pk;
    }
}

// ---------------- launch ----------------
extern "C" void kernel_launch(void* const* d_in, const int* in_sizes, int n_in,
                              void* d_out, int out_size, void* d_ws, size_t ws_size,
                              hipStream_t stream) {
  const float* hidden = (const float*)d_in[0];
  const float* kvs    = (const float*)d_in[1];
  const float* Wq     = (const float*)d_in[2];
  const float* Wkv    = (const float*)d_in[3];
  const float* Wo     = (const float*)d_in[4];
  const float* relb   = (const float*)d_in[5];
  float* out = (float*)d_out;

  char* ws = (char*)d_ws;
  bf16* WqT  = (bf16*)(ws + (size_t)0);           // 2 MB
  bf16* WkvT = (bf16*)(ws + ((size_t)2 << 20));   // 4 MB
  bf16* WoT  = (bf16*)(ws + ((size_t)6 << 20));   // 2 MB
  bf16* Ob   = (bf16*)(ws + ((size_t)8 << 20));   // 8 MB [B,S,E]
  bf16* Qb   = (bf16*)(ws + ((size_t)16 << 20));  // 8 MB [B,H,S,D]
  bf16* Kb   = (bf16*)(ws + ((size_t)24 << 20));  // 8 MB [B,H,K,D]
  bf16* Vt   = (bf16*)(ws + ((size_t)32 << 20));  // 8 MB [B,H,D,K]
  float* LUT = (float*)(ws + ((size_t)40 << 20)); // 256 KB

  // weights transpose+cast + bias LUT, one launch
  prep_k<<<dim3(64, 32, 4), dim3(32, 8), 0, stream>>>(Wq, Wkv, Wo, relb, WqT, WkvT, WoT, LUT);
  // Q (x log2e), K, V projections — reads f32 inputs directly (cast fused)
  gemm_qkv_k<<<dim3(32, 24), 256, 0, stream>>>(hidden, kvs, WqT, WkvT, Qb, Kb, Vt);
  // attention -> Ob
  attn_k<<<dim3(16, 32), 512, 0, stream>>>(Qb, Kb, Vt, LUT, Ob);
  // out = Ob @ Wo
  gemm_o_k<<<dim3(32, 16), 256, 0, stream>>>(Ob, WoT, out);
}